// Round 17
// baseline (148.980 us; speedup 1.0000x reference)
//
#include <hip/hip_runtime.h>
#include <hip/hip_bf16.h>

#define B_   2
#define H_   16
#define LQ_  1024
#define LKV_ 2048
#define D_   64
#define E_   1024

typedef __attribute__((ext_vector_type(8))) _Float16 f16x8;
typedef __attribute__((ext_vector_type(4))) _Float16 f16x4;
typedef __attribute__((ext_vector_type(4))) float   f32x4;
typedef __attribute__((ext_vector_type(4))) unsigned short u16x4;

__device__ __forceinline__ void gload16_lds(const void* g, void* l) {
    __builtin_amdgcn_global_load_lds(
        (const __attribute__((address_space(1))) unsigned int*)g,
        (__attribute__((address_space(3))) unsigned int*)l, 16, 0, 0);
}
__device__ __forceinline__ unsigned short f2bf(float f) {
    union { float f; unsigned u; } v; v.f = f;
    unsigned r = v.u + 0x7FFFu + ((v.u >> 16) & 1u);
    return (unsigned short)(r >> 16);
}
__device__ __forceinline__ float bf2f(unsigned short u) {
    union { unsigned u; float f; } v; v.u = ((unsigned)u) << 16; return v.f;
}

// ---------------- one-wave mask-dtype probe ----------------
__global__ void probe17(const void* __restrict__ msk, int* __restrict__ modep) {
    int lane = threadIdx.x;
    int notInt = 0, notF32 = 0, notBF = 0;
    for (int i = lane; i < 256; i += 64) {
        unsigned v = ((const unsigned*)msk)[i * 997];
        if (v > 1u) notInt = 1;
        if (v != 0u && v != 0x3F800000u) notF32 = 1;
        if (v != 0u && v != 0x3F80u && v != 0x3F800000u && v != 0x3F803F80u) notBF = 1;
    }
    notInt = __any(notInt); notF32 = __any(notF32); notBF = __any(notBF);
    if (lane == 0) *modep = !notInt ? 0 : (!notF32 ? 1 : (!notBF ? 2 : 3));
}

// ---------------- streaming canonicalization (mask -> TRANSPOSED bits [t][row]) --------
__global__ void canon17_all(
    const float* __restrict__ x,  const float* __restrict__ ctx,
    const float* __restrict__ wq, const float* __restrict__ wk,
    const float* __restrict__ wv, const float* __restrict__ fw,
    const float* __restrict__ fb, const void* __restrict__ msk,
    _Float16* __restrict__ xh,  _Float16* __restrict__ ch,
    _Float16* __restrict__ wqh, _Float16* __restrict__ wkvh,
    _Float16* __restrict__ fwh, float* __restrict__ fbf,
    unsigned long long* __restrict__ Mbt, const int* __restrict__ modep)
{
    const int mmode = *modep;
    const int total = 1376384;
    const int stride = gridDim.x * blockDim.x;
    for (int idx = blockIdx.x * blockDim.x + threadIdx.x; idx < total; idx += stride) {
        if (idx < 1310720) {
            const float* src; _Float16* dst; int rel;
            if (idx < 262144)       { src = x;   dst = xh;   rel = idx; }
            else if (idx < 786432)  { src = ctx; dst = ch;   rel = idx - 262144; }
            else if (idx < 917504)  { src = wq;  dst = wqh;  rel = idx - 786432; }
            else if (idx < 1048576) { src = wk;  dst = wkvh; rel = idx - 917504; }
            else if (idx < 1179648) { src = wv;  dst = wkvh + (size_t)E_ * E_; rel = idx - 1048576; }
            else                    { src = fw;  dst = fwh;  rel = idx - 1179648; }
            f32x4 a = ((const f32x4*)src)[2 * rel], b = ((const f32x4*)src)[2 * rel + 1];
            f16x8 o;
            o[0] = (_Float16)a.x; o[1] = (_Float16)a.y; o[2] = (_Float16)a.z; o[3] = (_Float16)a.w;
            o[4] = (_Float16)b.x; o[5] = (_Float16)b.y; o[6] = (_Float16)b.z; o[7] = (_Float16)b.w;
            ((f16x8*)dst)[rel] = o;
        } else if (idx < 1310848) {
            int rel = idx - 1310720;
#pragma unroll
            for (int j = 0; j < 8; ++j) fbf[rel * 8 + j] = fb[rel * 8 + j];
        } else {
            int rel = idx - 1310848;           // rel = row*32 + t
            const size_t base = (size_t)rel * 64;
            unsigned long long v = 0;
            if (mmode == 0) {
                const int* p = (const int*)msk + base;
#pragma unroll
                for (int j = 0; j < 64; ++j) if (p[j] != 0) v |= 1ull << j;
            } else if (mmode == 1) {
                const float* p = (const float*)msk + base;
#pragma unroll
                for (int j = 0; j < 64; ++j) if (p[j] != 0.0f) v |= 1ull << j;
            } else if (mmode == 2) {
                const unsigned short* p = (const unsigned short*)msk + base;
#pragma unroll
                for (int j = 0; j < 64; ++j) if (p[j] != 0) v |= 1ull << j;
            } else {
                const unsigned char* p = (const unsigned char*)msk + base;
#pragma unroll
                for (int j = 0; j < 64; ++j) if (p[j] != 0) v |= 1ull << j;
            }
            Mbt[(rel & 31) * 2048 + (rel >> 5)] = v;   // transposed: [t][b*LQ+q]
        }
    }
}

// ---------------- fused Q + K|V projection GEMM: BK=64, swizzled, double-buffered ----
__global__ __launch_bounds__(256) void gemm17_qkv(
    const _Float16* __restrict__ xh, const _Float16* __restrict__ ch,
    const _Float16* __restrict__ wqh, const _Float16* __restrict__ wkvh,
    _Float16* __restrict__ Qh, _Float16* __restrict__ Kh, _Float16* __restrict__ Vt)
{
    __shared__ __align__(16) _Float16 As[2][128 * 64];
    __shared__ __align__(16) _Float16 Bs[2][128 * 64];

    const int bid = blockIdx.x;
    const bool isQ = bid < 128;
    const _Float16* A; const _Float16* W; int tm, tn;
    if (isQ) { A = xh; W = wqh; tm = bid >> 3; tn = bid & 7; }
    else     { int b2 = bid - 128; A = ch; W = wkvh; tm = b2 >> 4; tn = b2 & 15; }

    const int tid = threadIdx.x;
    const int w = tid >> 6, lane = tid & 63;
    const int g = lane >> 4, c = lane & 15;
    const int wr = w >> 1, wc = w & 1;
    const int rowS = lane >> 3, slot = lane & 7;
    const int stSwz = ((slot ^ (rowS & 7)) << 4);
    const int swz0 = ((g ^ (c & 7)) << 4);
    const int swz1 = (((4 + g) ^ (c & 7)) << 4);

    f32x4 acc[4][4];
#pragma unroll
    for (int i = 0; i < 4; i++)
#pragma unroll
        for (int j = 0; j < 4; j++) acc[i][j] = f32x4{0.f, 0.f, 0.f, 0.f};

    const size_t rowB = (size_t)E_ * 2;
    const char* gAbase = (const char*)A + (size_t)(tm * 128) * rowB;
    const char* gBbase = (const char*)W + (size_t)(tn * 128) * rowB;

#pragma unroll
    for (int j = 0; j < 4; ++j) {
        int rloc = w * 32 + j * 8 + rowS;
        gload16_lds(gAbase + (size_t)rloc * rowB + stSwz,
                    (char*)As[0] + (w * 32 + j * 8) * 128 + lane * 16);
        gload16_lds(gBbase + (size_t)rloc * rowB + stSwz,
                    (char*)Bs[0] + (w * 32 + j * 8) * 128 + lane * 16);
    }
    __syncthreads();

    for (int kt = 0; kt < 16; ++kt) {
        if (kt < 15) {
            const int nb = (kt + 1) & 1;
#pragma unroll
            for (int j = 0; j < 4; ++j) {
                int rloc = w * 32 + j * 8 + rowS;
                gload16_lds(gAbase + (size_t)rloc * rowB + (kt + 1) * 128 + stSwz,
                            (char*)As[nb] + (w * 32 + j * 8) * 128 + lane * 16);
                gload16_lds(gBbase + (size_t)rloc * rowB + (kt + 1) * 128 + stSwz,
                            (char*)Bs[nb] + (w * 32 + j * 8) * 128 + lane * 16);
            }
        }
        const int cb = kt & 1;

        f16x8 bF[4][2];
#pragma unroll
        for (int ni = 0; ni < 4; ni++) {
            const char* bp = (const char*)Bs[cb] + (wc * 64 + ni * 16 + c) * 128;
            bF[ni][0] = *(const f16x8*)(bp + swz0);
            bF[ni][1] = *(const f16x8*)(bp + swz1);
        }
#pragma unroll
        for (int mi = 0; mi < 4; mi++) {
            const char* ap = (const char*)As[cb] + (wr * 64 + mi * 16 + c) * 128;
            f16x8 a0 = *(const f16x8*)(ap + swz0);
            f16x8 a1 = *(const f16x8*)(ap + swz1);
#pragma unroll
            for (int ni = 0; ni < 4; ni++) {
                acc[mi][ni] = __builtin_amdgcn_mfma_f32_16x16x32_f16(a0, bF[ni][0], acc[mi][ni], 0, 0, 0);
                acc[mi][ni] = __builtin_amdgcn_mfma_f32_16x16x32_f16(a1, bF[ni][1], acc[mi][ni], 0, 0, 0);
            }
        }
        __syncthreads();
    }

#pragma unroll
    for (int mi = 0; mi < 4; mi++) {
#pragma unroll
        for (int ni = 0; ni < 4; ni++) {
#pragma unroll
            for (int r = 0; r < 4; r++) {
                int R  = tm * 128 + wr * 64 + mi * 16 + g * 4 + r;
                int Cc = tn * 128 + wc * 64 + ni * 16 + c;
                float v = acc[mi][ni][r];
                if (isQ) {
                    int b = R >> 10, q = R & 1023;
                    int h = Cc >> 6, d = Cc & 63;
                    // 0.125 * log2(e): attention works in exp2 domain
                    Qh[((size_t)(b * H_ + h) * LQ_ + q) * D_ + d] = (_Float16)(v * 0.18033688011112042f);
                } else {
                    int b = R >> 11, k = R & 2047;
                    int isV = Cc >> 10, cc2 = Cc & 1023;
                    int h = cc2 >> 6, d = cc2 & 63;
                    if (!isV)
                        Kh[((size_t)(b * H_ + h) * LKV_ + k) * D_ + d] = (_Float16)v;
                    else {
                        size_t bh = (size_t)(b * H_ + h);
                        Vt[((bh * (LKV_ / 64) + (k >> 6)) * D_ + d) * 64 + (k & 63)] = (_Float16)v;
                    }
                }
            }
        }
    }
}

// ---------------- FC GEMM: BK=64, swizzled, double-buffered ----------------
__global__ __launch_bounds__(256) void gemm17_fc(
    const _Float16* __restrict__ A, const _Float16* __restrict__ W,
    const float* __restrict__ bias, float* __restrict__ Cout)
{
    __shared__ __align__(16) _Float16 As[2][128 * 64];
    __shared__ __align__(16) _Float16 Bs[2][128 * 64];

    const int tm = blockIdx.x >> 3, tn = blockIdx.x & 7;
    const int tid = threadIdx.x;
    const int w = tid >> 6, lane = tid & 63;
    const int g = lane >> 4, c = lane & 15;
    const int wr = w >> 1, wc = w & 1;
    const int rowS = lane >> 3, slot = lane & 7;
    const int stSwz = ((slot ^ (rowS & 7)) << 4);
    const int swz0 = ((g ^ (c & 7)) << 4);
    const int swz1 = (((4 + g) ^ (c & 7)) << 4);

    f32x4 acc[4][4];
#pragma unroll
    for (int i = 0; i < 4; i++)
#pragma unroll
        for (int j = 0; j < 4; j++) acc[i][j] = f32x4{0.f, 0.f, 0.f, 0.f};

    const size_t rowB = (size_t)E_ * 2;
    const char* gAbase = (const char*)A + (size_t)(tm * 128) * rowB;
    const char* gBbase = (const char*)W + (size_t)(tn * 128) * rowB;

#pragma unroll
    for (int j = 0; j < 4; ++j) {
        int rloc = w * 32 + j * 8 + rowS;
        gload16_lds(gAbase + (size_t)rloc * rowB + stSwz,
                    (char*)As[0] + (w * 32 + j * 8) * 128 + lane * 16);
        gload16_lds(gBbase + (size_t)rloc * rowB + stSwz,
                    (char*)Bs[0] + (w * 32 + j * 8) * 128 + lane * 16);
    }
    __syncthreads();

    for (int kt = 0; kt < 16; ++kt) {
        if (kt < 15) {
            const int nb = (kt + 1) & 1;
#pragma unroll
            for (int j = 0; j < 4; ++j) {
                int rloc = w * 32 + j * 8 + rowS;
                gload16_lds(gAbase + (size_t)rloc * rowB + (kt + 1) * 128 + stSwz,
                            (char*)As[nb] + (w * 32 + j * 8) * 128 + lane * 16);
                gload16_lds(gBbase + (size_t)rloc * rowB + (kt + 1) * 128 + stSwz,
                            (char*)Bs[nb] + (w * 32 + j * 8) * 128 + lane * 16);
            }
        }
        const int cb = kt & 1;

        f16x8 bF[4][2];
#pragma unroll
        for (int ni = 0; ni < 4; ni++) {
            const char* bp = (const char*)Bs[cb] + (wc * 64 + ni * 16 + c) * 128;
            bF[ni][0] = *(const f16x8*)(bp + swz0);
            bF[ni][1] = *(const f16x8*)(bp + swz1);
        }
#pragma unroll
        for (int mi = 0; mi < 4; mi++) {
            const char* ap = (const char*)As[cb] + (wr * 64 + mi * 16 + c) * 128;
            f16x8 a0 = *(const f16x8*)(ap + swz0);
            f16x8 a1 = *(const f16x8*)(ap + swz1);
#pragma unroll
            for (int ni = 0; ni < 4; ni++) {
                acc[mi][ni] = __builtin_amdgcn_mfma_f32_16x16x32_f16(a0, bF[ni][0], acc[mi][ni], 0, 0, 0);
                acc[mi][ni] = __builtin_amdgcn_mfma_f32_16x16x32_f16(a1, bF[ni][1], acc[mi][ni], 0, 0, 0);
            }
        }
        __syncthreads();
    }

#pragma unroll
    for (int mi = 0; mi < 4; mi++)
#pragma unroll
        for (int ni = 0; ni < 4; ni++)
#pragma unroll
            for (int r = 0; r < 4; r++) {
                int R  = tm * 128 + wr * 64 + mi * 16 + g * 4 + r;
                int Cc = tn * 128 + wc * 64 + ni * 16 + c;
                Cout[(size_t)R * E_ + Cc] = acc[mi][ni][r] + bias[Cc];
            }
}

// ---------------- flash attention: CROSS-BLOCK 2-way kv split, 256thr, 32KB LDS ------
// Grid 1024 = 8 xcd x {4 bh x 16 qt x 2 kv-half}. Block 256 = 4 waves, wave = 16 q.
// Writes bf16 O-partials + f32 (m,lsum) to workspace; combine17 merges.
__global__ __launch_bounds__(256) void attn17_kernel(
    const _Float16* __restrict__ Qh,   // [B,H,LQ,D] pre-scaled by 0.125*log2e
    const _Float16* __restrict__ Kh,   // [B,H,LKV,D]
    const _Float16* __restrict__ Vt,   // [B*H][LKV/64][D][64] tiled
    const unsigned long long* __restrict__ Mbt,  // [32][B*LQ] transposed bitmask
    unsigned short* __restrict__ Opart,  // [2][32][1024][64] bf16 partials
    float* __restrict__ Ml2)             // [2][32][1024] float2 (m, lsum)
{
    __shared__ __align__(16) char ldsraw[32768];  // dbuf x (K 8KB | V 8KB)

    const int bid0 = blockIdx.x;
    const int xcd = bid0 & 7, jj = bid0 >> 3;        // jj 0..127
    const int bh = xcd * 4 + (jj >> 5);              // K/V + Q L2-local per XCD
    const int rem = jj & 31;
    const int qt = rem >> 1, ksHalf = rem & 1;
    const int b = bh >> 4, h = bh & 15; (void)h; (void)b;
    const int tid = threadIdx.x;
    const int w = tid >> 6, lane = tid & 63;
    const int g = lane >> 4, c = lane & 15;
    const int q0 = qt * 64 + w * 16;

    f16x8 qf[2];
#pragma unroll
    for (int ks = 0; ks < 2; ++ks)
        qf[ks] = *(const f16x8*)&Qh[((size_t)bh * LQ_ + q0 + c) * D_ + ks * 32 + g * 8];

    f32x4 o[4];
#pragma unroll
    for (int dt = 0; dt < 4; dt++) o[dt] = f32x4{0.f, 0.f, 0.f, 0.f};
    float m = -1e30f, lsum = 0.f;

    const int rowS = (lane >> 3);
    const int stOffBase = (rowS * 128) + (((lane & 7) ^ (rowS & 7)) * 16);
    const char* kTileB = (const char*)Kh + (size_t)bh * (LKV_ * D_ * 2) + (size_t)ksHalf * 16 * 8192;
    const char* vTileB = (const char*)Vt + (size_t)bh * (LKV_ * D_ * 2) + (size_t)ksHalf * 16 * 8192;

    int rdOff[2];
#pragma unroll
    for (int ks = 0; ks < 2; ++ks)
        rdOff[ks] = c * 128 + (((ks * 4 + g) ^ (c & 7)) * 16);

    const int srcLo = (((g & 1) << 1) * 16 + c) << 2;
    const int srcHi = ((((g & 1) << 1) + 1) * 16 + c) << 2;
    const bool hiSel = (g >= 2);

    const int mRowIdx = (bh >> 4) * LQ_ + q0 + c;
    const size_t mTile0 = (size_t)(ksHalf * 16) * 2048 + mRowIdx;

    // prologue: stage tile 0 into buffer 0 (4 waves cover 64 rows x 128B each of K and V)
    {
#pragma unroll
        for (int j = 0; j < 2; ++j) {
            gload16_lds(kTileB + (w * 2048 + j * 1024) + stOffBase, ldsraw + (w * 2048 + j * 1024));
            gload16_lds(vTileB + (w * 2048 + j * 1024) + stOffBase, ldsraw + 8192 + (w * 2048 + j * 1024));
        }
    }
    __syncthreads();

    for (int t = 0; t < 16; ++t) {
        if (t < 15) {
            const char* kt = kTileB + (size_t)(t + 1) * 8192;
            const char* vt = vTileB + (size_t)(t + 1) * 8192;
            char* dst = ldsraw + ((t + 1) & 1) * 16384;
#pragma unroll
            for (int j = 0; j < 2; ++j) {
                gload16_lds(kt + (w * 2048 + j * 1024) + stOffBase, dst + (w * 2048 + j * 1024));
                gload16_lds(vt + (w * 2048 + j * 1024) + stOffBase, dst + 8192 + (w * 2048 + j * 1024));
            }
        }

        const char* bufp = ldsraw + (t & 1) * 16384;

        f32x4 s[4];
#pragma unroll
        for (int nt = 0; nt < 4; ++nt) {
            f32x4 accS = f32x4{0.f, 0.f, 0.f, 0.f};
#pragma unroll
            for (int ks = 0; ks < 2; ++ks) {
                f16x8 kf = *(const f16x8*)(bufp + nt * 2048 + rdOff[ks]);
                accS = __builtin_amdgcn_mfma_f32_16x16x32_f16(kf, qf[ks], accS, 0, 0, 0);
            }
            s[nt] = accS;
        }
        unsigned long long mks = Mbt[mTile0 + (size_t)t * 2048] >> (g * 4);
#pragma unroll
        for (int nt = 0; nt < 4; ++nt) {
            unsigned nib = (unsigned)(mks >> (nt * 16)) & 0xFu;
            if (nib & 1u) s[nt][0] = -1e9f;
            if (nib & 2u) s[nt][1] = -1e9f;
            if (nib & 4u) s[nt][2] = -1e9f;
            if (nib & 8u) s[nt][3] = -1e9f;
        }
        float t0 = fmaxf(fmaxf(s[0][0], s[0][1]), fmaxf(s[0][2], s[0][3]));
        float t1 = fmaxf(fmaxf(s[1][0], s[1][1]), fmaxf(s[1][2], s[1][3]));
        float t2 = fmaxf(fmaxf(s[2][0], s[2][1]), fmaxf(s[2][2], s[2][3]));
        float t3 = fmaxf(fmaxf(s[3][0], s[3][1]), fmaxf(s[3][2], s[3][3]));
        float tmax = fmaxf(fmaxf(t0, t1), fmaxf(t2, t3));
        tmax = fmaxf(tmax, __shfl_xor(tmax, 16, 64));
        tmax = fmaxf(tmax, __shfl_xor(tmax, 32, 64));
        if (!__all(tmax - m <= 8.0f)) {
            float mn = fmaxf(m, tmax);
            float scl = exp2f(m - mn);
            m = mn;
            lsum *= scl;
#pragma unroll
            for (int dt = 0; dt < 4; dt++)
#pragma unroll
                for (int r = 0; r < 4; r++) o[dt][r] *= scl;
        }
        float ts = 0.f;
#pragma unroll
        for (int nt = 0; nt < 4; ++nt) {
            float p0 = exp2f(s[nt][0] - m);
            float p1 = exp2f(s[nt][1] - m);
            float p2 = exp2f(s[nt][2] - m);
            float p3 = exp2f(s[nt][3] - m);
            s[nt][0] = p0; s[nt][1] = p1; s[nt][2] = p2; s[nt][3] = p3;
            ts += (p0 + p1) + (p2 + p3);
        }
        ts += __shfl_xor(ts, 16, 64);
        ts += __shfl_xor(ts, 32, 64);
        lsum += ts;
        int pk[4][2];
#pragma unroll
        for (int nt = 0; nt < 4; ++nt) {
            pk[nt][0] = __builtin_bit_cast(int, __builtin_amdgcn_cvt_pkrtz(s[nt][0], s[nt][1]));
            pk[nt][1] = __builtin_bit_cast(int, __builtin_amdgcn_cvt_pkrtz(s[nt][2], s[nt][3]));
        }
#pragma unroll
        for (int ks = 0; ks < 2; ++ks) {
            const int ntL = 2 * ks, ntH = 2 * ks + 1;
            int aL0 = __builtin_amdgcn_ds_bpermute(srcLo, pk[ntL][0]);
            int aL1 = __builtin_amdgcn_ds_bpermute(srcLo, pk[ntL][1]);
            int aH0 = __builtin_amdgcn_ds_bpermute(srcHi, pk[ntL][0]);
            int aH1 = __builtin_amdgcn_ds_bpermute(srcHi, pk[ntL][1]);
            int bL0 = __builtin_amdgcn_ds_bpermute(srcLo, pk[ntH][0]);
            int bL1 = __builtin_amdgcn_ds_bpermute(srcLo, pk[ntH][1]);
            int bH0 = __builtin_amdgcn_ds_bpermute(srcHi, pk[ntH][0]);
            int bH1 = __builtin_amdgcn_ds_bpermute(srcHi, pk[ntH][1]);
            int u[4];
            u[0] = hiSel ? bL0 : aL0;
            u[1] = hiSel ? bL1 : aL1;
            u[2] = hiSel ? bH0 : aH0;
            u[3] = hiSel ? bH1 : aH1;
            f16x8 pf;
            {
                union { int i[4]; f16x8 v; } cvt;
                cvt.i[0] = u[0]; cvt.i[1] = u[1]; cvt.i[2] = u[2]; cvt.i[3] = u[3];
                pf = cvt.v;
            }
#pragma unroll
            for (int dt = 0; dt < 4; ++dt) {
                f16x8 vf = *(const f16x8*)(bufp + 8192 + dt * 2048 + rdOff[ks]);
                o[dt] = __builtin_amdgcn_mfma_f32_16x16x32_f16(vf, pf, o[dt], 0, 0, 0);
            }
        }
        __syncthreads();
    }

    // ---- write partials: Opart[ksHalf][bh][q0+c][d], Ml2[ksHalf][bh][q] = (m, lsum) ----
    unsigned short* opBase = Opart + (((size_t)(ksHalf * 32 + bh) * LQ_ + (q0 + c)) * D_);
#pragma unroll
    for (int dt = 0; dt < 4; ++dt) {
        u16x4 pv;
#pragma unroll
        for (int r = 0; r < 4; ++r) pv[r] = f2bf(o[dt][r]);
        *(u16x4*)(opBase + dt * 16 + 4 * g) = pv;
    }
    if (lane < 16) {
        float* mlp = Ml2 + ((size_t)(ksHalf * 32 + bh) * LQ_ + (q0 + lane)) * 2;
        mlp[0] = m;
        mlp[1] = lsum;
    }
}

// ---------------- combine partials -> Ob f16 [B,LQ,E] ----------------
__global__ __launch_bounds__(256) void combine17(
    const unsigned short* __restrict__ Opart,
    const float* __restrict__ Ml2,
    _Float16* __restrict__ O)
{
    int idx = blockIdx.x * 256 + threadIdx.x;      // 524288 = 32 bh x 1024 q x 16 d4
    int bh = idx >> 14;
    int q  = (idx >> 4) & 1023;
    int d4 = idx & 15;
    const float* ml0 = Ml2 + ((size_t)bh * LQ_ + q) * 2;
    const float* ml1 = Ml2 + ((size_t)(32 + bh) * LQ_ + q) * 2;
    float m0 = ml0[0], l0 = ml0[1];
    float m1 = ml1[0], l1 = ml1[1];
    float M  = fmaxf(m0, m1);
    float e0 = exp2f(m0 - M), e1 = exp2f(m1 - M);
    float inv = 1.0f / (l0 * e0 + l1 * e1);
    u16x4 a = *(const u16x4*)(Opart + ((size_t)bh * LQ_ + q) * D_ + d4 * 4);
    u16x4 bq = *(const u16x4*)(Opart + ((size_t)(32 + bh) * LQ_ + q) * D_ + d4 * 4);
    f16x4 outv;
#pragma unroll
    for (int j = 0; j < 4; ++j)
        outv[j] = (_Float16)((bf2f(a[j]) * e0 + bf2f(bq[j]) * e1) * inv);
    int b = bh >> 4, h = bh & 15;
    *(f16x4*)&O[((size_t)(b * LQ_ + q)) * E_ + h * 64 + d4 * 4] = outv;
}

extern "C" void kernel_launch(void* const* d_in, const int* in_sizes, int n_in,
                              void* d_out, int out_size, void* d_ws, size_t ws_size,
                              hipStream_t stream)
{
    const float* x   = (const float*)d_in[0];
    const float* ctx = (const float*)d_in[1];
    const void*  msk = d_in[2];
    const float* Wq  = (const float*)d_in[3];
    const float* Wk  = (const float*)d_in[4];
    const float* Wv  = (const float*)d_in[5];
    const float* fcw = (const float*)d_in[6];
    const float* fcb = (const float*)d_in[7];
    float* out = (float*)d_out;

    char* ws = (char*)d_ws;
    size_t off = 0;
    auto alloc = [&](size_t bytes) { char* p = ws + off; off += (bytes + 255) & ~255ull; return p; };

    int* modep = (int*)alloc(256);
    unsigned long long* Mbt = (unsigned long long*)alloc((size_t)B_ * LQ_ * (LKV_ / 64) * 8);
    _Float16* xh   = (_Float16*)alloc((size_t)B_ * LQ_ * E_ * 2);
    _Float16* ch   = (_Float16*)alloc((size_t)B_ * LKV_ * E_ * 2);
    _Float16* wqh  = (_Float16*)alloc((size_t)E_ * E_ * 2);
    _Float16* wkvh = (_Float16*)alloc((size_t)2 * E_ * E_ * 2);
    _Float16* fwh  = (_Float16*)alloc((size_t)E_ * E_ * 2);
    float*    fbf  = (float*)alloc((size_t)E_ * 4);
    _Float16* Qh   = (_Float16*)alloc((size_t)B_ * H_ * LQ_ * D_ * 2);
    _Float16* Kh   = (_Float16*)alloc((size_t)B_ * H_ * LKV_ * D_ * 2);
    _Float16* Vt   = (_Float16*)alloc((size_t)B_ * H_ * LKV_ * D_ * 2);
    _Float16* Ob   = xh;  // safe alias: gemm17_qkv (last reader of xh) finishes before combine writes Ob
    // partial buffers alias dead-after-qkv regions:
    unsigned short* Opart = (unsigned short*)ch;   // 8.39MB fits ch (8.39MB)
    float* Ml2 = (float*)wqh;                      // 0.52MB fits wqh (2MB); wqh dead after qkv
    (void)ws_size; (void)in_sizes; (void)n_in; (void)out_size;

    probe17<<<1, 64, 0, stream>>>(msk, modep);

    canon17_all<<<2048, 256, 0, stream>>>(x, ctx, Wq, Wk, Wv, fcw, fcb, msk,
                                          xh, ch, wqh, wkvh, fwh, fbf, Mbt, modep);

    gemm17_qkv<<<640, 256, 0, stream>>>(xh, ch, wqh, wkvh, Qh, Kh, Vt);

    attn17_kernel<<<1024, 256, 0, stream>>>(Qh, Kh, Vt, Mbt, Opart, Ml2);

    combine17<<<2048, 256, 0, stream>>>(Opart, Ml2, Ob);

    gemm17_fc<<<128, 256, 0, stream>>>(Ob, fwh, fbf, out);
}

// Round 18
// 134.052 us; speedup vs baseline: 1.1114x; 1.1114x over previous
//
#include <hip/hip_runtime.h>
#include <hip/hip_bf16.h>

#define B_   2
#define H_   16
#define LQ_  1024
#define LKV_ 2048
#define D_   64
#define E_   1024

typedef __attribute__((ext_vector_type(8))) _Float16 f16x8;
typedef __attribute__((ext_vector_type(4))) float   f32x4;

__device__ __forceinline__ void gload16_lds(const void* g, void* l) {
    __builtin_amdgcn_global_load_lds(
        (const __attribute__((address_space(1))) unsigned int*)g,
        (__attribute__((address_space(3))) unsigned int*)l, 16, 0, 0);
}

// ---------------- one-wave mask-dtype probe ----------------
__global__ void probe18(const void* __restrict__ msk, int* __restrict__ modep) {
    int lane = threadIdx.x;
    int notInt = 0, notF32 = 0, notBF = 0;
    for (int i = lane; i < 256; i += 64) {
        unsigned v = ((const unsigned*)msk)[i * 997];
        if (v > 1u) notInt = 1;
        if (v != 0u && v != 0x3F800000u) notF32 = 1;
        if (v != 0u && v != 0x3F80u && v != 0x3F800000u && v != 0x3F803F80u) notBF = 1;
    }
    notInt = __any(notInt); notF32 = __any(notF32); notBF = __any(notBF);
    if (lane == 0) *modep = !notInt ? 0 : (!notF32 ? 1 : (!notBF ? 2 : 3));
}

// ---------------- streaming canonicalization (mask -> TRANSPOSED bits [t][row]) --------
__global__ void canon18_all(
    const float* __restrict__ x,  const float* __restrict__ ctx,
    const float* __restrict__ wq, const float* __restrict__ wk,
    const float* __restrict__ wv, const float* __restrict__ fw,
    const float* __restrict__ fb, const void* __restrict__ msk,
    _Float16* __restrict__ xh,  _Float16* __restrict__ ch,
    _Float16* __restrict__ wqh, _Float16* __restrict__ wkvh,
    _Float16* __restrict__ fwh, float* __restrict__ fbf,
    unsigned long long* __restrict__ Mbt, const int* __restrict__ modep)
{
    const int mmode = *modep;
    const int total = 1376384;
    const int stride = gridDim.x * blockDim.x;
    for (int idx = blockIdx.x * blockDim.x + threadIdx.x; idx < total; idx += stride) {
        if (idx < 1310720) {
            const float* src; _Float16* dst; int rel;
            if (idx < 262144)       { src = x;   dst = xh;   rel = idx; }
            else if (idx < 786432)  { src = ctx; dst = ch;   rel = idx - 262144; }
            else if (idx < 917504)  { src = wq;  dst = wqh;  rel = idx - 786432; }
            else if (idx < 1048576) { src = wk;  dst = wkvh; rel = idx - 917504; }
            else if (idx < 1179648) { src = wv;  dst = wkvh + (size_t)E_ * E_; rel = idx - 1048576; }
            else                    { src = fw;  dst = fwh;  rel = idx - 1179648; }
            f32x4 a = ((const f32x4*)src)[2 * rel], b = ((const f32x4*)src)[2 * rel + 1];
            f16x8 o;
            o[0] = (_Float16)a.x; o[1] = (_Float16)a.y; o[2] = (_Float16)a.z; o[3] = (_Float16)a.w;
            o[4] = (_Float16)b.x; o[5] = (_Float16)b.y; o[6] = (_Float16)b.z; o[7] = (_Float16)b.w;
            ((f16x8*)dst)[rel] = o;
        } else if (idx < 1310848) {
            int rel = idx - 1310720;
#pragma unroll
            for (int j = 0; j < 8; ++j) fbf[rel * 8 + j] = fb[rel * 8 + j];
        } else {
            int rel = idx - 1310848;           // rel = row*32 + t
            const size_t base = (size_t)rel * 64;
            unsigned long long v = 0;
            if (mmode == 0) {
                const int* p = (const int*)msk + base;
#pragma unroll
                for (int j = 0; j < 64; ++j) if (p[j] != 0) v |= 1ull << j;
            } else if (mmode == 1) {
                const float* p = (const float*)msk + base;
#pragma unroll
                for (int j = 0; j < 64; ++j) if (p[j] != 0.0f) v |= 1ull << j;
            } else if (mmode == 2) {
                const unsigned short* p = (const unsigned short*)msk + base;
#pragma unroll
                for (int j = 0; j < 64; ++j) if (p[j] != 0) v |= 1ull << j;
            } else {
                const unsigned char* p = (const unsigned char*)msk + base;
#pragma unroll
                for (int j = 0; j < 64; ++j) if (p[j] != 0) v |= 1ull << j;
            }
            Mbt[(rel & 31) * 2048 + (rel >> 5)] = v;   // transposed: [t][b*LQ+q]
        }
    }
}

// ---------------- fused Q + K|V projection GEMM: 64x128 tiles, BK=64, dbuf ----------
// blocks 0..255: Q proj (tm=bid>>3 of 32, tn=bid&7); 256..1279: K|V (tm=b2>>4 of 64, tn=b2&15)
__global__ __launch_bounds__(256) void gemm18_qkv(
    const _Float16* __restrict__ xh, const _Float16* __restrict__ ch,
    const _Float16* __restrict__ wqh, const _Float16* __restrict__ wkvh,
    _Float16* __restrict__ Qh, _Float16* __restrict__ Kh, _Float16* __restrict__ Vt)
{
    __shared__ __align__(16) _Float16 As[2][64 * 64];    // 2 x 8KB
    __shared__ __align__(16) _Float16 Bs[2][128 * 64];   // 2 x 16KB

    const int bid = blockIdx.x;
    const bool isQ = bid < 256;
    const _Float16* A; const _Float16* W; int tm, tn;
    if (isQ) { A = xh; W = wqh; tm = bid >> 3; tn = bid & 7; }
    else     { int b2 = bid - 256; A = ch; W = wkvh; tm = b2 >> 4; tn = b2 & 15; }

    const int tid = threadIdx.x;
    const int w = tid >> 6, lane = tid & 63;
    const int g = lane >> 4, c = lane & 15;
    const int wr = w >> 1, wc = w & 1;
    const int rowS = lane >> 3, slot = lane & 7;
    const int stSwz = ((slot ^ (rowS & 7)) << 4);
    const int swz0 = ((g ^ (c & 7)) << 4);
    const int swz1 = (((4 + g) ^ (c & 7)) << 4);

    f32x4 acc[2][4];
#pragma unroll
    for (int i = 0; i < 2; i++)
#pragma unroll
        for (int j = 0; j < 4; j++) acc[i][j] = f32x4{0.f, 0.f, 0.f, 0.f};

    const size_t rowB = (size_t)E_ * 2;
    const char* gAbase = (const char*)A + (size_t)(tm * 64) * rowB;
    const char* gBbase = (const char*)W + (size_t)(tn * 128) * rowB;

    // prologue: stage tile 0
#pragma unroll
    for (int j = 0; j < 2; ++j) {
        int rloc = w * 16 + j * 8 + rowS;
        gload16_lds(gAbase + (size_t)rloc * rowB + stSwz,
                    (char*)As[0] + (w * 16 + j * 8) * 128 + lane * 16);
    }
#pragma unroll
    for (int j = 0; j < 4; ++j) {
        int rloc = w * 32 + j * 8 + rowS;
        gload16_lds(gBbase + (size_t)rloc * rowB + stSwz,
                    (char*)Bs[0] + (w * 32 + j * 8) * 128 + lane * 16);
    }
    __syncthreads();

    for (int kt = 0; kt < 16; ++kt) {
        if (kt < 15) {
            const int nb = (kt + 1) & 1;
#pragma unroll
            for (int j = 0; j < 2; ++j) {
                int rloc = w * 16 + j * 8 + rowS;
                gload16_lds(gAbase + (size_t)rloc * rowB + (kt + 1) * 128 + stSwz,
                            (char*)As[nb] + (w * 16 + j * 8) * 128 + lane * 16);
            }
#pragma unroll
            for (int j = 0; j < 4; ++j) {
                int rloc = w * 32 + j * 8 + rowS;
                gload16_lds(gBbase + (size_t)rloc * rowB + (kt + 1) * 128 + stSwz,
                            (char*)Bs[nb] + (w * 32 + j * 8) * 128 + lane * 16);
            }
        }
        const int cb = kt & 1;

        f16x8 bF[4][2];
#pragma unroll
        for (int ni = 0; ni < 4; ni++) {
            const char* bp = (const char*)Bs[cb] + (wc * 64 + ni * 16 + c) * 128;
            bF[ni][0] = *(const f16x8*)(bp + swz0);
            bF[ni][1] = *(const f16x8*)(bp + swz1);
        }
#pragma unroll
        for (int mi = 0; mi < 2; mi++) {
            const char* ap = (const char*)As[cb] + (wr * 32 + mi * 16 + c) * 128;
            f16x8 a0 = *(const f16x8*)(ap + swz0);
            f16x8 a1 = *(const f16x8*)(ap + swz1);
#pragma unroll
            for (int ni = 0; ni < 4; ni++) {
                acc[mi][ni] = __builtin_amdgcn_mfma_f32_16x16x32_f16(a0, bF[ni][0], acc[mi][ni], 0, 0, 0);
                acc[mi][ni] = __builtin_amdgcn_mfma_f32_16x16x32_f16(a1, bF[ni][1], acc[mi][ni], 0, 0, 0);
            }
        }
        __syncthreads();
    }

#pragma unroll
    for (int mi = 0; mi < 2; mi++) {
#pragma unroll
        for (int ni = 0; ni < 4; ni++) {
#pragma unroll
            for (int r = 0; r < 4; r++) {
                int R  = tm * 64 + wr * 32 + mi * 16 + g * 4 + r;
                int Cc = tn * 128 + wc * 64 + ni * 16 + c;
                float v = acc[mi][ni][r];
                if (isQ) {
                    int b = R >> 10, q = R & 1023;
                    int h = Cc >> 6, d = Cc & 63;
                    // 0.125 * log2(e): attention works in exp2 domain
                    Qh[((size_t)(b * H_ + h) * LQ_ + q) * D_ + d] = (_Float16)(v * 0.18033688011112042f);
                } else {
                    int b = R >> 11, k = R & 2047;
                    int isV = Cc >> 10, cc2 = Cc & 1023;
                    int h = cc2 >> 6, d = cc2 & 63;
                    if (!isV)
                        Kh[((size_t)(b * H_ + h) * LKV_ + k) * D_ + d] = (_Float16)v;
                    else {
                        size_t bh = (size_t)(b * H_ + h);
                        Vt[((bh * (LKV_ / 64) + (k >> 6)) * D_ + d) * 64 + (k & 63)] = (_Float16)v;
                    }
                }
            }
        }
    }
}

// ---------------- FC GEMM: 64x128 tiles (256 blocks = 1/CU), BK=64, dbuf ------------
__global__ __launch_bounds__(256) void gemm18_fc(
    const _Float16* __restrict__ A, const _Float16* __restrict__ W,
    const float* __restrict__ bias, float* __restrict__ Cout)
{
    __shared__ __align__(16) _Float16 As[2][64 * 64];
    __shared__ __align__(16) _Float16 Bs[2][128 * 64];

    const int tm = blockIdx.x >> 3, tn = blockIdx.x & 7;   // 32 x 8
    const int tid = threadIdx.x;
    const int w = tid >> 6, lane = tid & 63;
    const int g = lane >> 4, c = lane & 15;
    const int wr = w >> 1, wc = w & 1;
    const int rowS = lane >> 3, slot = lane & 7;
    const int stSwz = ((slot ^ (rowS & 7)) << 4);
    const int swz0 = ((g ^ (c & 7)) << 4);
    const int swz1 = (((4 + g) ^ (c & 7)) << 4);

    f32x4 acc[2][4];
#pragma unroll
    for (int i = 0; i < 2; i++)
#pragma unroll
        for (int j = 0; j < 4; j++) acc[i][j] = f32x4{0.f, 0.f, 0.f, 0.f};

    const size_t rowB = (size_t)E_ * 2;
    const char* gAbase = (const char*)A + (size_t)(tm * 64) * rowB;
    const char* gBbase = (const char*)W + (size_t)(tn * 128) * rowB;

#pragma unroll
    for (int j = 0; j < 2; ++j) {
        int rloc = w * 16 + j * 8 + rowS;
        gload16_lds(gAbase + (size_t)rloc * rowB + stSwz,
                    (char*)As[0] + (w * 16 + j * 8) * 128 + lane * 16);
    }
#pragma unroll
    for (int j = 0; j < 4; ++j) {
        int rloc = w * 32 + j * 8 + rowS;
        gload16_lds(gBbase + (size_t)rloc * rowB + stSwz,
                    (char*)Bs[0] + (w * 32 + j * 8) * 128 + lane * 16);
    }
    __syncthreads();

    for (int kt = 0; kt < 16; ++kt) {
        if (kt < 15) {
            const int nb = (kt + 1) & 1;
#pragma unroll
            for (int j = 0; j < 2; ++j) {
                int rloc = w * 16 + j * 8 + rowS;
                gload16_lds(gAbase + (size_t)rloc * rowB + (kt + 1) * 128 + stSwz,
                            (char*)As[nb] + (w * 16 + j * 8) * 128 + lane * 16);
            }
#pragma unroll
            for (int j = 0; j < 4; ++j) {
                int rloc = w * 32 + j * 8 + rowS;
                gload16_lds(gBbase + (size_t)rloc * rowB + (kt + 1) * 128 + stSwz,
                            (char*)Bs[nb] + (w * 32 + j * 8) * 128 + lane * 16);
            }
        }
        const int cb = kt & 1;

        f16x8 bF[4][2];
#pragma unroll
        for (int ni = 0; ni < 4; ni++) {
            const char* bp = (const char*)Bs[cb] + (wc * 64 + ni * 16 + c) * 128;
            bF[ni][0] = *(const f16x8*)(bp + swz0);
            bF[ni][1] = *(const f16x8*)(bp + swz1);
        }
#pragma unroll
        for (int mi = 0; mi < 2; mi++) {
            const char* ap = (const char*)As[cb] + (wr * 32 + mi * 16 + c) * 128;
            f16x8 a0 = *(const f16x8*)(ap + swz0);
            f16x8 a1 = *(const f16x8*)(ap + swz1);
#pragma unroll
            for (int ni = 0; ni < 4; ni++) {
                acc[mi][ni] = __builtin_amdgcn_mfma_f32_16x16x32_f16(a0, bF[ni][0], acc[mi][ni], 0, 0, 0);
                acc[mi][ni] = __builtin_amdgcn_mfma_f32_16x16x32_f16(a1, bF[ni][1], acc[mi][ni], 0, 0, 0);
            }
        }
        __syncthreads();
    }

#pragma unroll
    for (int mi = 0; mi < 2; mi++)
#pragma unroll
        for (int ni = 0; ni < 4; ni++)
#pragma unroll
            for (int r = 0; r < 4; r++) {
                int R  = tm * 64 + wr * 32 + mi * 16 + g * 4 + r;
                int Cc = tn * 128 + wc * 64 + ni * 16 + c;
                Cout[(size_t)R * E_ + Cc] = acc[mi][ni][r] + bias[Cc];
            }
}

// ---------------- flash attention: r16 champion, verbatim ----------------
// Grid 512 (8 xcd x 4 bh x 16 q-tiles of 64). Block 512 = 8 waves:
// ws = w>>2 (kv half, 16 tiles each), wq = w&3 (16-q subtile). LDS 64KB.
__global__ __launch_bounds__(512) void attn18_kernel(
    const _Float16* __restrict__ Qh,   // [B,H,LQ,D] pre-scaled by 0.125*log2e
    const _Float16* __restrict__ Kh,   // [B,H,LKV,D]
    const _Float16* __restrict__ Vt,   // [B*H][LKV/64][D][64] tiled
    const unsigned long long* __restrict__ Mbt,  // [32][B*LQ] transposed bitmask
    _Float16* __restrict__ O)          // [B,LQ,E] f16
{
    __shared__ __align__(16) char ldsraw[65536];

    const int bid0 = blockIdx.x;
    const int xcd = bid0 & 7, jj = bid0 >> 3;
    const int bh = xcd * 4 + (jj >> 4);
    const int qt = jj & 15;
    const int b = bh >> 4, h = bh & 15;
    const int tid = threadIdx.x;
    const int w = tid >> 6, lane = tid & 63;
    const int g = lane >> 4, c = lane & 15;
    const int ws = w >> 2, wq = w & 3;
    const int q0 = qt * 64 + wq * 16;

    char* half = ldsraw + ws * 32768;

    f16x8 qf[2];
#pragma unroll
    for (int ks = 0; ks < 2; ++ks)
        qf[ks] = *(const f16x8*)&Qh[((size_t)bh * LQ_ + q0 + c) * D_ + ks * 32 + g * 8];

    f32x4 o[4];
#pragma unroll
    for (int dt = 0; dt < 4; dt++) o[dt] = f32x4{0.f, 0.f, 0.f, 0.f};
    float m = -1e30f, lsum = 0.f;

    const int rowS = (lane >> 3);
    const int stOffBase = (rowS * 128) + (((lane & 7) ^ (rowS & 7)) * 16);
    const char* kTileB = (const char*)Kh + (size_t)bh * (LKV_ * D_ * 2) + (size_t)ws * 16 * 8192;
    const char* vTileB = (const char*)Vt + (size_t)bh * (LKV_ * D_ * 2) + (size_t)ws * 16 * 8192;

    int rdOff[2];
#pragma unroll
    for (int ks = 0; ks < 2; ++ks)
        rdOff[ks] = c * 128 + (((ks * 4 + g) ^ (c & 7)) * 16);

    const int srcLo = (((g & 1) << 1) * 16 + c) << 2;
    const int srcHi = ((((g & 1) << 1) + 1) * 16 + c) << 2;
    const bool hiSel = (g >= 2);

    const int mRowIdx = b * LQ_ + q0 + c;
    const size_t mTile0 = (size_t)(ws * 16) * 2048 + mRowIdx;

    {
#pragma unroll
        for (int j = 0; j < 2; ++j) {
            gload16_lds(kTileB + (wq * 2048 + j * 1024) + stOffBase, half + (wq * 2048 + j * 1024));
            gload16_lds(vTileB + (wq * 2048 + j * 1024) + stOffBase, half + 8192 + (wq * 2048 + j * 1024));
        }
    }
    __syncthreads();

    for (int t = 0; t < 16; ++t) {
        if (t < 15) {
            const char* kt = kTileB + (size_t)(t + 1) * 8192;
            const char* vt = vTileB + (size_t)(t + 1) * 8192;
            char* dst = half + ((t + 1) & 1) * 16384;
#pragma unroll
            for (int j = 0; j < 2; ++j) {
                gload16_lds(kt + (wq * 2048 + j * 1024) + stOffBase, dst + (wq * 2048 + j * 1024));
                gload16_lds(vt + (wq * 2048 + j * 1024) + stOffBase, dst + 8192 + (wq * 2048 + j * 1024));
            }
        }

        const char* bufp = half + (t & 1) * 16384;

        f32x4 s[4];
#pragma unroll
        for (int nt = 0; nt < 4; ++nt) {
            f32x4 accS = f32x4{0.f, 0.f, 0.f, 0.f};
#pragma unroll
            for (int ks = 0; ks < 2; ++ks) {
                f16x8 kf = *(const f16x8*)(bufp + nt * 2048 + rdOff[ks]);
                accS = __builtin_amdgcn_mfma_f32_16x16x32_f16(kf, qf[ks], accS, 0, 0, 0);
            }
            s[nt] = accS;
        }
        unsigned long long mks = Mbt[mTile0 + (size_t)t * 2048] >> (g * 4);
#pragma unroll
        for (int nt = 0; nt < 4; ++nt) {
            unsigned nib = (unsigned)(mks >> (nt * 16)) & 0xFu;
            if (nib & 1u) s[nt][0] = -1e9f;
            if (nib & 2u) s[nt][1] = -1e9f;
            if (nib & 4u) s[nt][2] = -1e9f;
            if (nib & 8u) s[nt][3] = -1e9f;
        }
        float t0 = fmaxf(fmaxf(s[0][0], s[0][1]), fmaxf(s[0][2], s[0][3]));
        float t1 = fmaxf(fmaxf(s[1][0], s[1][1]), fmaxf(s[1][2], s[1][3]));
        float t2 = fmaxf(fmaxf(s[2][0], s[2][1]), fmaxf(s[2][2], s[2][3]));
        float t3 = fmaxf(fmaxf(s[3][0], s[3][1]), fmaxf(s[3][2], s[3][3]));
        float tmax = fmaxf(fmaxf(t0, t1), fmaxf(t2, t3));
        tmax = fmaxf(tmax, __shfl_xor(tmax, 16, 64));
        tmax = fmaxf(tmax, __shfl_xor(tmax, 32, 64));
        if (!__all(tmax - m <= 8.0f)) {
            float mn = fmaxf(m, tmax);
            float scl = exp2f(m - mn);
            m = mn;
            lsum *= scl;
#pragma unroll
            for (int dt = 0; dt < 4; dt++)
#pragma unroll
                for (int r = 0; r < 4; r++) o[dt][r] *= scl;
        }
        float ts = 0.f;
#pragma unroll
        for (int nt = 0; nt < 4; ++nt) {
            float p0 = exp2f(s[nt][0] - m);
            float p1 = exp2f(s[nt][1] - m);
            float p2 = exp2f(s[nt][2] - m);
            float p3 = exp2f(s[nt][3] - m);
            s[nt][0] = p0; s[nt][1] = p1; s[nt][2] = p2; s[nt][3] = p3;
            ts += (p0 + p1) + (p2 + p3);
        }
        ts += __shfl_xor(ts, 16, 64);
        ts += __shfl_xor(ts, 32, 64);
        lsum += ts;
        int pk[4][2];
#pragma unroll
        for (int nt = 0; nt < 4; ++nt) {
            pk[nt][0] = __builtin_bit_cast(int, __builtin_amdgcn_cvt_pkrtz(s[nt][0], s[nt][1]));
            pk[nt][1] = __builtin_bit_cast(int, __builtin_amdgcn_cvt_pkrtz(s[nt][2], s[nt][3]));
        }
#pragma unroll
        for (int ks = 0; ks < 2; ++ks) {
            const int ntL = 2 * ks, ntH = 2 * ks + 1;
            int aL0 = __builtin_amdgcn_ds_bpermute(srcLo, pk[ntL][0]);
            int aL1 = __builtin_amdgcn_ds_bpermute(srcLo, pk[ntL][1]);
            int aH0 = __builtin_amdgcn_ds_bpermute(srcHi, pk[ntL][0]);
            int aH1 = __builtin_amdgcn_ds_bpermute(srcHi, pk[ntL][1]);
            int bL0 = __builtin_amdgcn_ds_bpermute(srcLo, pk[ntH][0]);
            int bL1 = __builtin_amdgcn_ds_bpermute(srcLo, pk[ntH][1]);
            int bH0 = __builtin_amdgcn_ds_bpermute(srcHi, pk[ntH][0]);
            int bH1 = __builtin_amdgcn_ds_bpermute(srcHi, pk[ntH][1]);
            int u[4];
            u[0] = hiSel ? bL0 : aL0;
            u[1] = hiSel ? bL1 : aL1;
            u[2] = hiSel ? bH0 : aH0;
            u[3] = hiSel ? bH1 : aH1;
            f16x8 pf;
            {
                union { int i[4]; f16x8 v; } cvt;
                cvt.i[0] = u[0]; cvt.i[1] = u[1]; cvt.i[2] = u[2]; cvt.i[3] = u[3];
                pf = cvt.v;
            }
#pragma unroll
            for (int dt = 0; dt < 4; ++dt) {
                f16x8 vf = *(const f16x8*)(bufp + 8192 + dt * 2048 + rdOff[ks]);
                o[dt] = __builtin_amdgcn_mfma_f32_16x16x32_f16(vf, pf, o[dt], 0, 0, 0);
            }
        }
        __syncthreads();
    }

    float* OfP = (float*)ldsraw;                  // [128][68]
    float* Ml  = (float*)(ldsraw + 34816);        // [128][2]
#pragma unroll
    for (int dt = 0; dt < 4; ++dt)
#pragma unroll
        for (int r = 0; r < 4; r++)
            OfP[(w * 16 + c) * 68 + dt * 16 + 4 * g + r] = o[dt][r];
    if (lane < 16) {
        Ml[(w * 16 + lane) * 2 + 0] = m;
        Ml[(w * 16 + lane) * 2 + 1] = lsum;
    }
    __syncthreads();

    const int d = tid & 63;
    const int qlBase = tid >> 6;
#pragma unroll
    for (int pass = 0; pass < 8; ++pass) {
        int ql = pass * 8 + qlBase;          // 0..63
        float m0 = Ml[ql * 2], l0 = Ml[ql * 2 + 1];
        float m1 = Ml[(64 + ql) * 2], l1 = Ml[(64 + ql) * 2 + 1];
        float M  = fmaxf(m0, m1);
        float e0 = exp2f(m0 - M), e1 = exp2f(m1 - M);
        float L  = l0 * e0 + l1 * e1;
        float acc = OfP[ql * 68 + d] * e0 + OfP[(64 + ql) * 68 + d] * e1;
        O[((size_t)b * LQ_ + qt * 64 + ql) * E_ + h * 64 + d] = (_Float16)(acc / L);
    }
}

extern "C" void kernel_launch(void* const* d_in, const int* in_sizes, int n_in,
                              void* d_out, int out_size, void* d_ws, size_t ws_size,
                              hipStream_t stream)
{
    const float* x   = (const float*)d_in[0];
    const float* ctx = (const float*)d_in[1];
    const void*  msk = d_in[2];
    const float* Wq  = (const float*)d_in[3];
    const float* Wk  = (const float*)d_in[4];
    const float* Wv  = (const float*)d_in[5];
    const float* fcw = (const float*)d_in[6];
    const float* fcb = (const float*)d_in[7];
    float* out = (float*)d_out;

    char* ws = (char*)d_ws;
    size_t off = 0;
    auto alloc = [&](size_t bytes) { char* p = ws + off; off += (bytes + 255) & ~255ull; return p; };

    int* modep = (int*)alloc(256);
    unsigned long long* Mbt = (unsigned long long*)alloc((size_t)B_ * LQ_ * (LKV_ / 64) * 8);
    _Float16* xh   = (_Float16*)alloc((size_t)B_ * LQ_ * E_ * 2);
    _Float16* ch   = (_Float16*)alloc((size_t)B_ * LKV_ * E_ * 2);
    _Float16* wqh  = (_Float16*)alloc((size_t)E_ * E_ * 2);
    _Float16* wkvh = (_Float16*)alloc((size_t)2 * E_ * E_ * 2);
    _Float16* fwh  = (_Float16*)alloc((size_t)E_ * E_ * 2);
    float*    fbf  = (float*)alloc((size_t)E_ * 4);
    _Float16* Qh   = (_Float16*)alloc((size_t)B_ * H_ * LQ_ * D_ * 2);
    _Float16* Kh   = (_Float16*)alloc((size_t)B_ * H_ * LKV_ * D_ * 2);
    _Float16* Vt   = (_Float16*)alloc((size_t)B_ * H_ * LKV_ * D_ * 2);
    _Float16* Ob   = xh;  // safe alias: gemm18_qkv (last reader of xh) finishes before attn writes Ob
    (void)ws_size; (void)in_sizes; (void)n_in; (void)out_size;

    probe18<<<1, 64, 0, stream>>>(msk, modep);

    canon18_all<<<2048, 256, 0, stream>>>(x, ctx, Wq, Wk, Wv, fcw, fcb, msk,
                                          xh, ch, wqh, wkvh, fwh, fbf, Mbt, modep);

    gemm18_qkv<<<1280, 256, 0, stream>>>(xh, ch, wqh, wkvh, Qh, Kh, Vt);

    attn18_kernel<<<512, 512, 0, stream>>>(Qh, Kh, Vt, Mbt, Ob);

    gemm18_fc<<<256, 256, 0, stream>>>(Ob, fwh, fbf, out);
}

// Round 19
// 131.702 us; speedup vs baseline: 1.1312x; 1.0178x over previous
//
#include <hip/hip_runtime.h>
#include <hip/hip_bf16.h>

#define B_   2
#define H_   16
#define LQ_  1024
#define LKV_ 2048
#define D_   64
#define E_   1024

typedef __attribute__((ext_vector_type(8))) _Float16 f16x8;
typedef __attribute__((ext_vector_type(4))) float   f32x4;

__device__ __forceinline__ void gload16_lds(const void* g, void* l) {
    __builtin_amdgcn_global_load_lds(
        (const __attribute__((address_space(1))) unsigned int*)g,
        (__attribute__((address_space(3))) unsigned int*)l, 16, 0, 0);
}

// ---------------- one-wave mask-dtype probe ----------------
__global__ void probe19(const void* __restrict__ msk, int* __restrict__ modep) {
    int lane = threadIdx.x;
    int notInt = 0, notF32 = 0, notBF = 0;
    for (int i = lane; i < 256; i += 64) {
        unsigned v = ((const unsigned*)msk)[i * 997];
        if (v > 1u) notInt = 1;
        if (v != 0u && v != 0x3F800000u) notF32 = 1;
        if (v != 0u && v != 0x3F80u && v != 0x3F800000u && v != 0x3F803F80u) notBF = 1;
    }
    notInt = __any(notInt); notF32 = __any(notF32); notBF = __any(notBF);
    if (lane == 0) *modep = !notInt ? 0 : (!notF32 ? 1 : (!notBF ? 2 : 3));
}

// ---------------- streaming canonicalization (mask -> TRANSPOSED bits [t][row]) --------
__global__ void canon19_all(
    const float* __restrict__ x,  const float* __restrict__ ctx,
    const float* __restrict__ wq, const float* __restrict__ wk,
    const float* __restrict__ wv, const float* __restrict__ fw,
    const float* __restrict__ fb, const void* __restrict__ msk,
    _Float16* __restrict__ xh,  _Float16* __restrict__ ch,
    _Float16* __restrict__ wqh, _Float16* __restrict__ wkvh,
    _Float16* __restrict__ fwh, float* __restrict__ fbf,
    unsigned long long* __restrict__ Mbt, const int* __restrict__ modep)
{
    const int mmode = *modep;
    const int total = 1376384;
    const int stride = gridDim.x * blockDim.x;
    for (int idx = blockIdx.x * blockDim.x + threadIdx.x; idx < total; idx += stride) {
        if (idx < 1310720) {
            const float* src; _Float16* dst; int rel;
            if (idx < 262144)       { src = x;   dst = xh;   rel = idx; }
            else if (idx < 786432)  { src = ctx; dst = ch;   rel = idx - 262144; }
            else if (idx < 917504)  { src = wq;  dst = wqh;  rel = idx - 786432; }
            else if (idx < 1048576) { src = wk;  dst = wkvh; rel = idx - 917504; }
            else if (idx < 1179648) { src = wv;  dst = wkvh + (size_t)E_ * E_; rel = idx - 1048576; }
            else                    { src = fw;  dst = fwh;  rel = idx - 1179648; }
            f32x4 a = ((const f32x4*)src)[2 * rel], b = ((const f32x4*)src)[2 * rel + 1];
            f16x8 o;
            o[0] = (_Float16)a.x; o[1] = (_Float16)a.y; o[2] = (_Float16)a.z; o[3] = (_Float16)a.w;
            o[4] = (_Float16)b.x; o[5] = (_Float16)b.y; o[6] = (_Float16)b.z; o[7] = (_Float16)b.w;
            ((f16x8*)dst)[rel] = o;
        } else if (idx < 1310848) {
            int rel = idx - 1310720;
#pragma unroll
            for (int j = 0; j < 8; ++j) fbf[rel * 8 + j] = fb[rel * 8 + j];
        } else {
            int rel = idx - 1310848;           // rel = row*32 + t
            const size_t base = (size_t)rel * 64;
            unsigned long long v = 0;
            if (mmode == 0) {
                const int* p = (const int*)msk + base;
#pragma unroll
                for (int j = 0; j < 64; ++j) if (p[j] != 0) v |= 1ull << j;
            } else if (mmode == 1) {
                const float* p = (const float*)msk + base;
#pragma unroll
                for (int j = 0; j < 64; ++j) if (p[j] != 0.0f) v |= 1ull << j;
            } else if (mmode == 2) {
                const unsigned short* p = (const unsigned short*)msk + base;
#pragma unroll
                for (int j = 0; j < 64; ++j) if (p[j] != 0) v |= 1ull << j;
            } else {
                const unsigned char* p = (const unsigned char*)msk + base;
#pragma unroll
                for (int j = 0; j < 64; ++j) if (p[j] != 0) v |= 1ull << j;
            }
            Mbt[(rel & 31) * 2048 + (rel >> 5)] = v;   // transposed: [t][b*LQ+q]
        }
    }
}

// ---------------- fused Q + K|V projection GEMM: 64x128 tiles, BK=64, dbuf ----------
__global__ __launch_bounds__(256) void gemm19_qkv(
    const _Float16* __restrict__ xh, const _Float16* __restrict__ ch,
    const _Float16* __restrict__ wqh, const _Float16* __restrict__ wkvh,
    _Float16* __restrict__ Qh, _Float16* __restrict__ Kh, _Float16* __restrict__ Vt)
{
    __shared__ __align__(16) _Float16 As[2][64 * 64];    // 2 x 8KB
    __shared__ __align__(16) _Float16 Bs[2][128 * 64];   // 2 x 16KB

    const int bid = blockIdx.x;
    const bool isQ = bid < 256;
    const _Float16* A; const _Float16* W; int tm, tn;
    if (isQ) { A = xh; W = wqh; tm = bid >> 3; tn = bid & 7; }
    else     { int b2 = bid - 256; A = ch; W = wkvh; tm = b2 >> 4; tn = b2 & 15; }

    const int tid = threadIdx.x;
    const int w = tid >> 6, lane = tid & 63;
    const int g = lane >> 4, c = lane & 15;
    const int wr = w >> 1, wc = w & 1;
    const int rowS = lane >> 3, slot = lane & 7;
    const int stSwz = ((slot ^ (rowS & 7)) << 4);
    const int swz0 = ((g ^ (c & 7)) << 4);
    const int swz1 = (((4 + g) ^ (c & 7)) << 4);

    f32x4 acc[2][4];
#pragma unroll
    for (int i = 0; i < 2; i++)
#pragma unroll
        for (int j = 0; j < 4; j++) acc[i][j] = f32x4{0.f, 0.f, 0.f, 0.f};

    const size_t rowB = (size_t)E_ * 2;
    const char* gAbase = (const char*)A + (size_t)(tm * 64) * rowB;
    const char* gBbase = (const char*)W + (size_t)(tn * 128) * rowB;

#pragma unroll
    for (int j = 0; j < 2; ++j) {
        int rloc = w * 16 + j * 8 + rowS;
        gload16_lds(gAbase + (size_t)rloc * rowB + stSwz,
                    (char*)As[0] + (w * 16 + j * 8) * 128 + lane * 16);
    }
#pragma unroll
    for (int j = 0; j < 4; ++j) {
        int rloc = w * 32 + j * 8 + rowS;
        gload16_lds(gBbase + (size_t)rloc * rowB + stSwz,
                    (char*)Bs[0] + (w * 32 + j * 8) * 128 + lane * 16);
    }
    __syncthreads();

    for (int kt = 0; kt < 16; ++kt) {
        if (kt < 15) {
            const int nb = (kt + 1) & 1;
#pragma unroll
            for (int j = 0; j < 2; ++j) {
                int rloc = w * 16 + j * 8 + rowS;
                gload16_lds(gAbase + (size_t)rloc * rowB + (kt + 1) * 128 + stSwz,
                            (char*)As[nb] + (w * 16 + j * 8) * 128 + lane * 16);
            }
#pragma unroll
            for (int j = 0; j < 4; ++j) {
                int rloc = w * 32 + j * 8 + rowS;
                gload16_lds(gBbase + (size_t)rloc * rowB + (kt + 1) * 128 + stSwz,
                            (char*)Bs[nb] + (w * 32 + j * 8) * 128 + lane * 16);
            }
        }
        const int cb = kt & 1;

        f16x8 bF[4][2];
#pragma unroll
        for (int ni = 0; ni < 4; ni++) {
            const char* bp = (const char*)Bs[cb] + (wc * 64 + ni * 16 + c) * 128;
            bF[ni][0] = *(const f16x8*)(bp + swz0);
            bF[ni][1] = *(const f16x8*)(bp + swz1);
        }
#pragma unroll
        for (int mi = 0; mi < 2; mi++) {
            const char* ap = (const char*)As[cb] + (wr * 32 + mi * 16 + c) * 128;
            f16x8 a0 = *(const f16x8*)(ap + swz0);
            f16x8 a1 = *(const f16x8*)(ap + swz1);
#pragma unroll
            for (int ni = 0; ni < 4; ni++) {
                acc[mi][ni] = __builtin_amdgcn_mfma_f32_16x16x32_f16(a0, bF[ni][0], acc[mi][ni], 0, 0, 0);
                acc[mi][ni] = __builtin_amdgcn_mfma_f32_16x16x32_f16(a1, bF[ni][1], acc[mi][ni], 0, 0, 0);
            }
        }
        __syncthreads();
    }

#pragma unroll
    for (int mi = 0; mi < 2; mi++) {
#pragma unroll
        for (int ni = 0; ni < 4; ni++) {
#pragma unroll
            for (int r = 0; r < 4; r++) {
                int R  = tm * 64 + wr * 32 + mi * 16 + g * 4 + r;
                int Cc = tn * 128 + wc * 64 + ni * 16 + c;
                float v = acc[mi][ni][r];
                if (isQ) {
                    int b = R >> 10, q = R & 1023;
                    int h = Cc >> 6, d = Cc & 63;
                    // 0.125 * log2(e): attention works in exp2 domain
                    Qh[((size_t)(b * H_ + h) * LQ_ + q) * D_ + d] = (_Float16)(v * 0.18033688011112042f);
                } else {
                    int b = R >> 11, k = R & 2047;
                    int isV = Cc >> 10, cc2 = Cc & 1023;
                    int h = cc2 >> 6, d = cc2 & 63;
                    if (!isV)
                        Kh[((size_t)(b * H_ + h) * LKV_ + k) * D_ + d] = (_Float16)v;
                    else {
                        size_t bh = (size_t)(b * H_ + h);
                        Vt[((bh * (LKV_ / 64) + (k >> 6)) * D_ + d) * 64 + (k & 63)] = (_Float16)v;
                    }
                }
            }
        }
    }
}

// ---------------- FC GEMM: 64x128 tiles (256 blocks = 1/CU), BK=64, dbuf ------------
__global__ __launch_bounds__(256) void gemm19_fc(
    const _Float16* __restrict__ A, const _Float16* __restrict__ W,
    const float* __restrict__ bias, float* __restrict__ Cout)
{
    __shared__ __align__(16) _Float16 As[2][64 * 64];
    __shared__ __align__(16) _Float16 Bs[2][128 * 64];

    const int tm = blockIdx.x >> 3, tn = blockIdx.x & 7;   // 32 x 8
    const int tid = threadIdx.x;
    const int w = tid >> 6, lane = tid & 63;
    const int g = lane >> 4, c = lane & 15;
    const int wr = w >> 1, wc = w & 1;
    const int rowS = lane >> 3, slot = lane & 7;
    const int stSwz = ((slot ^ (rowS & 7)) << 4);
    const int swz0 = ((g ^ (c & 7)) << 4);
    const int swz1 = (((4 + g) ^ (c & 7)) << 4);

    f32x4 acc[2][4];
#pragma unroll
    for (int i = 0; i < 2; i++)
#pragma unroll
        for (int j = 0; j < 4; j++) acc[i][j] = f32x4{0.f, 0.f, 0.f, 0.f};

    const size_t rowB = (size_t)E_ * 2;
    const char* gAbase = (const char*)A + (size_t)(tm * 64) * rowB;
    const char* gBbase = (const char*)W + (size_t)(tn * 128) * rowB;

#pragma unroll
    for (int j = 0; j < 2; ++j) {
        int rloc = w * 16 + j * 8 + rowS;
        gload16_lds(gAbase + (size_t)rloc * rowB + stSwz,
                    (char*)As[0] + (w * 16 + j * 8) * 128 + lane * 16);
    }
#pragma unroll
    for (int j = 0; j < 4; ++j) {
        int rloc = w * 32 + j * 8 + rowS;
        gload16_lds(gBbase + (size_t)rloc * rowB + stSwz,
                    (char*)Bs[0] + (w * 32 + j * 8) * 128 + lane * 16);
    }
    __syncthreads();

    for (int kt = 0; kt < 16; ++kt) {
        if (kt < 15) {
            const int nb = (kt + 1) & 1;
#pragma unroll
            for (int j = 0; j < 2; ++j) {
                int rloc = w * 16 + j * 8 + rowS;
                gload16_lds(gAbase + (size_t)rloc * rowB + (kt + 1) * 128 + stSwz,
                            (char*)As[nb] + (w * 16 + j * 8) * 128 + lane * 16);
            }
#pragma unroll
            for (int j = 0; j < 4; ++j) {
                int rloc = w * 32 + j * 8 + rowS;
                gload16_lds(gBbase + (size_t)rloc * rowB + (kt + 1) * 128 + stSwz,
                            (char*)Bs[nb] + (w * 32 + j * 8) * 128 + lane * 16);
            }
        }
        const int cb = kt & 1;

        f16x8 bF[4][2];
#pragma unroll
        for (int ni = 0; ni < 4; ni++) {
            const char* bp = (const char*)Bs[cb] + (wc * 64 + ni * 16 + c) * 128;
            bF[ni][0] = *(const f16x8*)(bp + swz0);
            bF[ni][1] = *(const f16x8*)(bp + swz1);
        }
#pragma unroll
        for (int mi = 0; mi < 2; mi++) {
            const char* ap = (const char*)As[cb] + (wr * 32 + mi * 16 + c) * 128;
            f16x8 a0 = *(const f16x8*)(ap + swz0);
            f16x8 a1 = *(const f16x8*)(ap + swz1);
#pragma unroll
            for (int ni = 0; ni < 4; ni++) {
                acc[mi][ni] = __builtin_amdgcn_mfma_f32_16x16x32_f16(a0, bF[ni][0], acc[mi][ni], 0, 0, 0);
                acc[mi][ni] = __builtin_amdgcn_mfma_f32_16x16x32_f16(a1, bF[ni][1], acc[mi][ni], 0, 0, 0);
            }
        }
        __syncthreads();
    }

#pragma unroll
    for (int mi = 0; mi < 2; mi++)
#pragma unroll
        for (int ni = 0; ni < 4; ni++)
#pragma unroll
            for (int r = 0; r < 4; r++) {
                int R  = tm * 64 + wr * 32 + mi * 16 + g * 4 + r;
                int Cc = tn * 128 + wc * 64 + ni * 16 + c;
                Cout[(size_t)R * E_ + Cc] = acc[mi][ni][r] + bias[Cc];
            }
}

// ---------------- flash attention: r16 structure + lazy cross-lane softmax ----------
// Grid 512 (8 xcd x 4 bh x 16 q-tiles of 64). Block 512 = 8 waves:
// ws = w>>2 (kv half), wq = w&3 (16-q subtile). LDS 64KB.
// NEW: per-lane partial lsum (reduced once at end); per-lane defer-max test
// (cross-lane max shfl only when a rescale actually triggers).
__global__ __launch_bounds__(512) void attn19_kernel(
    const _Float16* __restrict__ Qh,   // [B,H,LQ,D] pre-scaled by 0.125*log2e
    const _Float16* __restrict__ Kh,   // [B,H,LKV,D]
    const _Float16* __restrict__ Vt,   // [B*H][LKV/64][D][64] tiled
    const unsigned long long* __restrict__ Mbt,  // [32][B*LQ] transposed bitmask
    _Float16* __restrict__ O)          // [B,LQ,E] f16
{
    __shared__ __align__(16) char ldsraw[65536];

    const int bid0 = blockIdx.x;
    const int xcd = bid0 & 7, jj = bid0 >> 3;
    const int bh = xcd * 4 + (jj >> 4);
    const int qt = jj & 15;
    const int b = bh >> 4, h = bh & 15;
    const int tid = threadIdx.x;
    const int w = tid >> 6, lane = tid & 63;
    const int g = lane >> 4, c = lane & 15;
    const int ws = w >> 2, wq = w & 3;
    const int q0 = qt * 64 + wq * 16;

    char* half = ldsraw + ws * 32768;

    f16x8 qf[2];
#pragma unroll
    for (int ks = 0; ks < 2; ++ks)
        qf[ks] = *(const f16x8*)&Qh[((size_t)bh * LQ_ + q0 + c) * D_ + ks * 32 + g * 8];

    f32x4 o[4];
#pragma unroll
    for (int dt = 0; dt < 4; dt++) o[dt] = f32x4{0.f, 0.f, 0.f, 0.f};
    float m = -1e30f, lsum = 0.f;   // lsum = PER-LANE partial (reduced at end)

    const int rowS = (lane >> 3);
    const int stOffBase = (rowS * 128) + (((lane & 7) ^ (rowS & 7)) * 16);
    const char* kTileB = (const char*)Kh + (size_t)bh * (LKV_ * D_ * 2) + (size_t)ws * 16 * 8192;
    const char* vTileB = (const char*)Vt + (size_t)bh * (LKV_ * D_ * 2) + (size_t)ws * 16 * 8192;

    int rdOff[2];
#pragma unroll
    for (int ks = 0; ks < 2; ++ks)
        rdOff[ks] = c * 128 + (((ks * 4 + g) ^ (c & 7)) * 16);

    const int srcLo = (((g & 1) << 1) * 16 + c) << 2;
    const int srcHi = ((((g & 1) << 1) + 1) * 16 + c) << 2;
    const bool hiSel = (g >= 2);

    const int mRowIdx = b * LQ_ + q0 + c;
    const size_t mTile0 = (size_t)(ws * 16) * 2048 + mRowIdx;

    {
#pragma unroll
        for (int j = 0; j < 2; ++j) {
            gload16_lds(kTileB + (wq * 2048 + j * 1024) + stOffBase, half + (wq * 2048 + j * 1024));
            gload16_lds(vTileB + (wq * 2048 + j * 1024) + stOffBase, half + 8192 + (wq * 2048 + j * 1024));
        }
    }
    __syncthreads();

    for (int t = 0; t < 16; ++t) {
        if (t < 15) {
            const char* kt = kTileB + (size_t)(t + 1) * 8192;
            const char* vt = vTileB + (size_t)(t + 1) * 8192;
            char* dst = half + ((t + 1) & 1) * 16384;
#pragma unroll
            for (int j = 0; j < 2; ++j) {
                gload16_lds(kt + (wq * 2048 + j * 1024) + stOffBase, dst + (wq * 2048 + j * 1024));
                gload16_lds(vt + (wq * 2048 + j * 1024) + stOffBase, dst + 8192 + (wq * 2048 + j * 1024));
            }
        }

        const char* bufp = half + (t & 1) * 16384;

        f32x4 s[4];
#pragma unroll
        for (int nt = 0; nt < 4; ++nt) {
            f32x4 accS = f32x4{0.f, 0.f, 0.f, 0.f};
#pragma unroll
            for (int ks = 0; ks < 2; ++ks) {
                f16x8 kf = *(const f16x8*)(bufp + nt * 2048 + rdOff[ks]);
                accS = __builtin_amdgcn_mfma_f32_16x16x32_f16(kf, qf[ks], accS, 0, 0, 0);
            }
            s[nt] = accS;
        }
        unsigned long long mks = Mbt[mTile0 + (size_t)t * 2048] >> (g * 4);
#pragma unroll
        for (int nt = 0; nt < 4; ++nt) {
            unsigned nib = (unsigned)(mks >> (nt * 16)) & 0xFu;
            if (nib & 1u) s[nt][0] = -1e9f;
            if (nib & 2u) s[nt][1] = -1e9f;
            if (nib & 4u) s[nt][2] = -1e9f;
            if (nib & 8u) s[nt][3] = -1e9f;
        }
        // ---- lazy defer-max: per-lane test, cross-lane reduce only on trigger ----
        float t0 = fmaxf(fmaxf(s[0][0], s[0][1]), fmaxf(s[0][2], s[0][3]));
        float t1 = fmaxf(fmaxf(s[1][0], s[1][1]), fmaxf(s[1][2], s[1][3]));
        float t2 = fmaxf(fmaxf(s[2][0], s[2][1]), fmaxf(s[2][2], s[2][3]));
        float t3 = fmaxf(fmaxf(s[3][0], s[3][1]), fmaxf(s[3][2], s[3][3]));
        float tmaxl = fmaxf(fmaxf(t0, t1), fmaxf(t2, t3));   // per-lane max (16 kv)
        if (!__all(tmaxl - m <= 8.0f)) {
            float tq = fmaxf(tmaxl, __shfl_xor(tmaxl, 16, 64));
            tq = fmaxf(tq, __shfl_xor(tq, 32, 64));          // per-q max (uniform over g)
            float mn = fmaxf(m, tq);
            float scl = exp2f(m - mn);
            m = mn;
            lsum *= scl;
#pragma unroll
            for (int dt = 0; dt < 4; dt++)
#pragma unroll
                for (int r = 0; r < 4; r++) o[dt][r] *= scl;
        }
        // ---- exp2 + PER-LANE accumulate (no per-tile cross-lane sum) ----
        float ts = 0.f;
#pragma unroll
        for (int nt = 0; nt < 4; ++nt) {
            float p0 = exp2f(s[nt][0] - m);
            float p1 = exp2f(s[nt][1] - m);
            float p2 = exp2f(s[nt][2] - m);
            float p3 = exp2f(s[nt][3] - m);
            s[nt][0] = p0; s[nt][1] = p1; s[nt][2] = p2; s[nt][3] = p3;
            ts += (p0 + p1) + (p2 + p3);
        }
        lsum += ts;
        int pk[4][2];
#pragma unroll
        for (int nt = 0; nt < 4; ++nt) {
            pk[nt][0] = __builtin_bit_cast(int, __builtin_amdgcn_cvt_pkrtz(s[nt][0], s[nt][1]));
            pk[nt][1] = __builtin_bit_cast(int, __builtin_amdgcn_cvt_pkrtz(s[nt][2], s[nt][3]));
        }
#pragma unroll
        for (int ks = 0; ks < 2; ++ks) {
            const int ntL = 2 * ks, ntH = 2 * ks + 1;
            int aL0 = __builtin_amdgcn_ds_bpermute(srcLo, pk[ntL][0]);
            int aL1 = __builtin_amdgcn_ds_bpermute(srcLo, pk[ntL][1]);
            int aH0 = __builtin_amdgcn_ds_bpermute(srcHi, pk[ntL][0]);
            int aH1 = __builtin_amdgcn_ds_bpermute(srcHi, pk[ntL][1]);
            int bL0 = __builtin_amdgcn_ds_bpermute(srcLo, pk[ntH][0]);
            int bL1 = __builtin_amdgcn_ds_bpermute(srcLo, pk[ntH][1]);
            int bH0 = __builtin_amdgcn_ds_bpermute(srcHi, pk[ntH][0]);
            int bH1 = __builtin_amdgcn_ds_bpermute(srcHi, pk[ntH][1]);
            int u[4];
            u[0] = hiSel ? bL0 : aL0;
            u[1] = hiSel ? bL1 : aL1;
            u[2] = hiSel ? bH0 : aH0;
            u[3] = hiSel ? bH1 : aH1;
            f16x8 pf;
            {
                union { int i[4]; f16x8 v; } cvt;
                cvt.i[0] = u[0]; cvt.i[1] = u[1]; cvt.i[2] = u[2]; cvt.i[3] = u[3];
                pf = cvt.v;
            }
#pragma unroll
            for (int dt = 0; dt < 4; ++dt) {
                f16x8 vf = *(const f16x8*)(bufp + 8192 + dt * 2048 + rdOff[ks]);
                o[dt] = __builtin_amdgcn_mfma_f32_16x16x32_f16(vf, pf, o[dt], 0, 0, 0);
            }
        }
        __syncthreads();
    }

    // ---- final per-q lsum reduce (2 shfl, ONCE instead of per tile) ----
    lsum += __shfl_xor(lsum, 16, 64);
    lsum += __shfl_xor(lsum, 32, 64);

    float* OfP = (float*)ldsraw;                  // [128][68]
    float* Ml  = (float*)(ldsraw + 34816);        // [128][2]
#pragma unroll
    for (int dt = 0; dt < 4; ++dt)
#pragma unroll
        for (int r = 0; r < 4; r++)
            OfP[(w * 16 + c) * 68 + dt * 16 + 4 * g + r] = o[dt][r];
    if (lane < 16) {
        Ml[(w * 16 + lane) * 2 + 0] = m;
        Ml[(w * 16 + lane) * 2 + 1] = lsum;
    }
    __syncthreads();

    const int d = tid & 63;
    const int qlBase = tid >> 6;
#pragma unroll
    for (int pass = 0; pass < 8; ++pass) {
        int ql = pass * 8 + qlBase;          // 0..63
        float m0 = Ml[ql * 2], l0 = Ml[ql * 2 + 1];
        float m1 = Ml[(64 + ql) * 2], l1 = Ml[(64 + ql) * 2 + 1];
        float M  = fmaxf(m0, m1);
        float e0 = exp2f(m0 - M), e1 = exp2f(m1 - M);
        float L  = l0 * e0 + l1 * e1;
        float acc = OfP[ql * 68 + d] * e0 + OfP[(64 + ql) * 68 + d] * e1;
        O[((size_t)b * LQ_ + qt * 64 + ql) * E_ + h * 64 + d] = (_Float16)(acc / L);
    }
}

extern "C" void kernel_launch(void* const* d_in, const int* in_sizes, int n_in,
                              void* d_out, int out_size, void* d_ws, size_t ws_size,
                              hipStream_t stream)
{
    const float* x   = (const float*)d_in[0];
    const float* ctx = (const float*)d_in[1];
    const void*  msk = d_in[2];
    const float* Wq  = (const float*)d_in[3];
    const float* Wk  = (const float*)d_in[4];
    const float* Wv  = (const float*)d_in[5];
    const float* fcw = (const float*)d_in[6];
    const float* fcb = (const float*)d_in[7];
    float* out = (float*)d_out;

    char* ws = (char*)d_ws;
    size_t off = 0;
    auto alloc = [&](size_t bytes) { char* p = ws + off; off += (bytes + 255) & ~255ull; return p; };

    int* modep = (int*)alloc(256);
    unsigned long long* Mbt = (unsigned long long*)alloc((size_t)B_ * LQ_ * (LKV_ / 64) * 8);
    _Float16* xh   = (_Float16*)alloc((size_t)B_ * LQ_ * E_ * 2);
    _Float16* ch   = (_Float16*)alloc((size_t)B_ * LKV_ * E_ * 2);
    _Float16* wqh  = (_Float16*)alloc((size_t)E_ * E_ * 2);
    _Float16* wkvh = (_Float16*)alloc((size_t)2 * E_ * E_ * 2);
    _Float16* fwh  = (_Float16*)alloc((size_t)E_ * E_ * 2);
    float*    fbf  = (float*)alloc((size_t)E_ * 4);
    _Float16* Qh   = (_Float16*)alloc((size_t)B_ * H_ * LQ_ * D_ * 2);
    _Float16* Kh   = (_Float16*)alloc((size_t)B_ * H_ * LKV_ * D_ * 2);
    _Float16* Vt   = (_Float16*)alloc((size_t)B_ * H_ * LKV_ * D_ * 2);
    _Float16* Ob   = xh;  // safe alias: gemm19_qkv (last reader of xh) finishes before attn writes Ob
    (void)ws_size; (void)in_sizes; (void)n_in; (void)out_size;

    probe19<<<1, 64, 0, stream>>>(msk, modep);

    canon19_all<<<2048, 256, 0, stream>>>(x, ctx, Wq, Wk, Wv, fcw, fcb, msk,
                                          xh, ch, wqh, wkvh, fwh, fbf, Mbt, modep);

    gemm19_qkv<<<1280, 256, 0, stream>>>(xh, ch, wqh, wkvh, Qh, Kh, Vt);

    attn19_kernel<<<512, 512, 0, stream>>>(Qh, Kh, Vt, Mbt, Ob);

    gemm19_fc<<<256, 256, 0, stream>>>(Ob, fwh, fbf, out);
}

// Round 20
// 128.344 us; speedup vs baseline: 1.1608x; 1.0262x over previous
//
#include <hip/hip_runtime.h>
#include <hip/hip_bf16.h>

#define B_   2
#define H_   16
#define LQ_  1024
#define LKV_ 2048
#define D_   64
#define E_   1024

typedef __attribute__((ext_vector_type(8))) _Float16 f16x8;
typedef __attribute__((ext_vector_type(4))) float   f32x4;
typedef __attribute__((ext_vector_type(2))) unsigned uint2v;

__device__ __forceinline__ void gload16_lds(const void* g, void* l) {
    __builtin_amdgcn_global_load_lds(
        (const __attribute__((address_space(1))) unsigned int*)g,
        (__attribute__((address_space(3))) unsigned int*)l, 16, 0, 0);
}

// ---------------- one-wave mask-dtype probe ----------------
__global__ void probe20(const void* __restrict__ msk, int* __restrict__ modep) {
    int lane = threadIdx.x;
    int notInt = 0, notF32 = 0, notBF = 0;
    for (int i = lane; i < 256; i += 64) {
        unsigned v = ((const unsigned*)msk)[i * 997];
        if (v > 1u) notInt = 1;
        if (v != 0u && v != 0x3F800000u) notF32 = 1;
        if (v != 0u && v != 0x3F80u && v != 0x3F800000u && v != 0x3F803F80u) notBF = 1;
    }
    notInt = __any(notInt); notF32 = __any(notF32); notBF = __any(notBF);
    if (lane == 0) *modep = !notInt ? 0 : (!notF32 ? 1 : (!notBF ? 2 : 3));
}

// ---------------- streaming canonicalization (mask -> TRANSPOSED bits [t][row]) --------
__global__ void canon20_all(
    const float* __restrict__ x,  const float* __restrict__ ctx,
    const float* __restrict__ wq, const float* __restrict__ wk,
    const float* __restrict__ wv, const float* __restrict__ fw,
    const float* __restrict__ fb, const void* __restrict__ msk,
    _Float16* __restrict__ xh,  _Float16* __restrict__ ch,
    _Float16* __restrict__ wqh, _Float16* __restrict__ wkvh,
    _Float16* __restrict__ fwh, float* __restrict__ fbf,
    unsigned long long* __restrict__ Mbt, const int* __restrict__ modep)
{
    const int mmode = *modep;
    const int total = 1376384;
    const int stride = gridDim.x * blockDim.x;
    for (int idx = blockIdx.x * blockDim.x + threadIdx.x; idx < total; idx += stride) {
        if (idx < 1310720) {
            const float* src; _Float16* dst; int rel;
            if (idx < 262144)       { src = x;   dst = xh;   rel = idx; }
            else if (idx < 786432)  { src = ctx; dst = ch;   rel = idx - 262144; }
            else if (idx < 917504)  { src = wq;  dst = wqh;  rel = idx - 786432; }
            else if (idx < 1048576) { src = wk;  dst = wkvh; rel = idx - 917504; }
            else if (idx < 1179648) { src = wv;  dst = wkvh + (size_t)E_ * E_; rel = idx - 1048576; }
            else                    { src = fw;  dst = fwh;  rel = idx - 1179648; }
            f32x4 a = ((const f32x4*)src)[2 * rel], b = ((const f32x4*)src)[2 * rel + 1];
            f16x8 o;
            o[0] = (_Float16)a.x; o[1] = (_Float16)a.y; o[2] = (_Float16)a.z; o[3] = (_Float16)a.w;
            o[4] = (_Float16)b.x; o[5] = (_Float16)b.y; o[6] = (_Float16)b.z; o[7] = (_Float16)b.w;
            ((f16x8*)dst)[rel] = o;
        } else if (idx < 1310848) {
            int rel = idx - 1310720;
#pragma unroll
            for (int j = 0; j < 8; ++j) fbf[rel * 8 + j] = fb[rel * 8 + j];
        } else {
            int rel = idx - 1310848;           // rel = row*32 + t
            const size_t base = (size_t)rel * 64;
            unsigned long long v = 0;
            if (mmode == 0) {
                const int* p = (const int*)msk + base;
#pragma unroll
                for (int j = 0; j < 64; ++j) if (p[j] != 0) v |= 1ull << j;
            } else if (mmode == 1) {
                const float* p = (const float*)msk + base;
#pragma unroll
                for (int j = 0; j < 64; ++j) if (p[j] != 0.0f) v |= 1ull << j;
            } else if (mmode == 2) {
                const unsigned short* p = (const unsigned short*)msk + base;
#pragma unroll
                for (int j = 0; j < 64; ++j) if (p[j] != 0) v |= 1ull << j;
            } else {
                const unsigned char* p = (const unsigned char*)msk + base;
#pragma unroll
                for (int j = 0; j < 64; ++j) if (p[j] != 0) v |= 1ull << j;
            }
            Mbt[(rel & 31) * 2048 + (rel >> 5)] = v;   // transposed: [t][b*LQ+q]
        }
    }
}

// ---------------- fused Q + K|V projection GEMM: 64x128 tiles, BK=64, dbuf ----------
__global__ __launch_bounds__(256) void gemm20_qkv(
    const _Float16* __restrict__ xh, const _Float16* __restrict__ ch,
    const _Float16* __restrict__ wqh, const _Float16* __restrict__ wkvh,
    _Float16* __restrict__ Qh, _Float16* __restrict__ Kh, _Float16* __restrict__ Vt)
{
    __shared__ __align__(16) _Float16 As[2][64 * 64];    // 2 x 8KB
    __shared__ __align__(16) _Float16 Bs[2][128 * 64];   // 2 x 16KB

    const int bid = blockIdx.x;
    const bool isQ = bid < 256;
    const _Float16* A; const _Float16* W; int tm, tn;
    if (isQ) { A = xh; W = wqh; tm = bid >> 3; tn = bid & 7; }
    else     { int b2 = bid - 256; A = ch; W = wkvh; tm = b2 >> 4; tn = b2 & 15; }

    const int tid = threadIdx.x;
    const int w = tid >> 6, lane = tid & 63;
    const int g = lane >> 4, c = lane & 15;
    const int wr = w >> 1, wc = w & 1;
    const int rowS = lane >> 3, slot = lane & 7;
    const int stSwz = ((slot ^ (rowS & 7)) << 4);
    const int swz0 = ((g ^ (c & 7)) << 4);
    const int swz1 = (((4 + g) ^ (c & 7)) << 4);

    f32x4 acc[2][4];
#pragma unroll
    for (int i = 0; i < 2; i++)
#pragma unroll
        for (int j = 0; j < 4; j++) acc[i][j] = f32x4{0.f, 0.f, 0.f, 0.f};

    const size_t rowB = (size_t)E_ * 2;
    const char* gAbase = (const char*)A + (size_t)(tm * 64) * rowB;
    const char* gBbase = (const char*)W + (size_t)(tn * 128) * rowB;

#pragma unroll
    for (int j = 0; j < 2; ++j) {
        int rloc = w * 16 + j * 8 + rowS;
        gload16_lds(gAbase + (size_t)rloc * rowB + stSwz,
                    (char*)As[0] + (w * 16 + j * 8) * 128 + lane * 16);
    }
#pragma unroll
    for (int j = 0; j < 4; ++j) {
        int rloc = w * 32 + j * 8 + rowS;
        gload16_lds(gBbase + (size_t)rloc * rowB + stSwz,
                    (char*)Bs[0] + (w * 32 + j * 8) * 128 + lane * 16);
    }
    __syncthreads();

    for (int kt = 0; kt < 16; ++kt) {
        if (kt < 15) {
            const int nb = (kt + 1) & 1;
#pragma unroll
            for (int j = 0; j < 2; ++j) {
                int rloc = w * 16 + j * 8 + rowS;
                gload16_lds(gAbase + (size_t)rloc * rowB + (kt + 1) * 128 + stSwz,
                            (char*)As[nb] + (w * 16 + j * 8) * 128 + lane * 16);
            }
#pragma unroll
            for (int j = 0; j < 4; ++j) {
                int rloc = w * 32 + j * 8 + rowS;
                gload16_lds(gBbase + (size_t)rloc * rowB + (kt + 1) * 128 + stSwz,
                            (char*)Bs[nb] + (w * 32 + j * 8) * 128 + lane * 16);
            }
        }
        const int cb = kt & 1;

        f16x8 bF[4][2];
#pragma unroll
        for (int ni = 0; ni < 4; ni++) {
            const char* bp = (const char*)Bs[cb] + (wc * 64 + ni * 16 + c) * 128;
            bF[ni][0] = *(const f16x8*)(bp + swz0);
            bF[ni][1] = *(const f16x8*)(bp + swz1);
        }
#pragma unroll
        for (int mi = 0; mi < 2; mi++) {
            const char* ap = (const char*)As[cb] + (wr * 32 + mi * 16 + c) * 128;
            f16x8 a0 = *(const f16x8*)(ap + swz0);
            f16x8 a1 = *(const f16x8*)(ap + swz1);
#pragma unroll
            for (int ni = 0; ni < 4; ni++) {
                acc[mi][ni] = __builtin_amdgcn_mfma_f32_16x16x32_f16(a0, bF[ni][0], acc[mi][ni], 0, 0, 0);
                acc[mi][ni] = __builtin_amdgcn_mfma_f32_16x16x32_f16(a1, bF[ni][1], acc[mi][ni], 0, 0, 0);
            }
        }
        __syncthreads();
    }

#pragma unroll
    for (int mi = 0; mi < 2; mi++) {
#pragma unroll
        for (int ni = 0; ni < 4; ni++) {
#pragma unroll
            for (int r = 0; r < 4; r++) {
                int R  = tm * 64 + wr * 32 + mi * 16 + g * 4 + r;
                int Cc = tn * 128 + wc * 64 + ni * 16 + c;
                float v = acc[mi][ni][r];
                if (isQ) {
                    int b = R >> 10, q = R & 1023;
                    int h = Cc >> 6, d = Cc & 63;
                    // 0.125 * log2(e): attention works in exp2 domain
                    Qh[((size_t)(b * H_ + h) * LQ_ + q) * D_ + d] = (_Float16)(v * 0.18033688011112042f);
                } else {
                    int b = R >> 11, k = R & 2047;
                    int isV = Cc >> 10, cc2 = Cc & 1023;
                    int h = cc2 >> 6, d = cc2 & 63;
                    if (!isV)
                        Kh[((size_t)(b * H_ + h) * LKV_ + k) * D_ + d] = (_Float16)v;
                    else {
                        size_t bh = (size_t)(b * H_ + h);
                        Vt[((bh * (LKV_ / 64) + (k >> 6)) * D_ + d) * 64 + (k & 63)] = (_Float16)v;
                    }
                }
            }
        }
    }
}

// ---------------- FC GEMM: 64x128 tiles (256 blocks = 1/CU), BK=64, dbuf ------------
__global__ __launch_bounds__(256) void gemm20_fc(
    const _Float16* __restrict__ A, const _Float16* __restrict__ W,
    const float* __restrict__ bias, float* __restrict__ Cout)
{
    __shared__ __align__(16) _Float16 As[2][64 * 64];
    __shared__ __align__(16) _Float16 Bs[2][128 * 64];

    const int tm = blockIdx.x >> 3, tn = blockIdx.x & 7;   // 32 x 8
    const int tid = threadIdx.x;
    const int w = tid >> 6, lane = tid & 63;
    const int g = lane >> 4, c = lane & 15;
    const int wr = w >> 1, wc = w & 1;
    const int rowS = lane >> 3, slot = lane & 7;
    const int stSwz = ((slot ^ (rowS & 7)) << 4);
    const int swz0 = ((g ^ (c & 7)) << 4);
    const int swz1 = (((4 + g) ^ (c & 7)) << 4);

    f32x4 acc[2][4];
#pragma unroll
    for (int i = 0; i < 2; i++)
#pragma unroll
        for (int j = 0; j < 4; j++) acc[i][j] = f32x4{0.f, 0.f, 0.f, 0.f};

    const size_t rowB = (size_t)E_ * 2;
    const char* gAbase = (const char*)A + (size_t)(tm * 64) * rowB;
    const char* gBbase = (const char*)W + (size_t)(tn * 128) * rowB;

#pragma unroll
    for (int j = 0; j < 2; ++j) {
        int rloc = w * 16 + j * 8 + rowS;
        gload16_lds(gAbase + (size_t)rloc * rowB + stSwz,
                    (char*)As[0] + (w * 16 + j * 8) * 128 + lane * 16);
    }
#pragma unroll
    for (int j = 0; j < 4; ++j) {
        int rloc = w * 32 + j * 8 + rowS;
        gload16_lds(gBbase + (size_t)rloc * rowB + stSwz,
                    (char*)Bs[0] + (w * 32 + j * 8) * 128 + lane * 16);
    }
    __syncthreads();

    for (int kt = 0; kt < 16; ++kt) {
        if (kt < 15) {
            const int nb = (kt + 1) & 1;
#pragma unroll
            for (int j = 0; j < 2; ++j) {
                int rloc = w * 16 + j * 8 + rowS;
                gload16_lds(gAbase + (size_t)rloc * rowB + (kt + 1) * 128 + stSwz,
                            (char*)As[nb] + (w * 16 + j * 8) * 128 + lane * 16);
            }
#pragma unroll
            for (int j = 0; j < 4; ++j) {
                int rloc = w * 32 + j * 8 + rowS;
                gload16_lds(gBbase + (size_t)rloc * rowB + (kt + 1) * 128 + stSwz,
                            (char*)Bs[nb] + (w * 32 + j * 8) * 128 + lane * 16);
            }
        }
        const int cb = kt & 1;

        f16x8 bF[4][2];
#pragma unroll
        for (int ni = 0; ni < 4; ni++) {
            const char* bp = (const char*)Bs[cb] + (wc * 64 + ni * 16 + c) * 128;
            bF[ni][0] = *(const f16x8*)(bp + swz0);
            bF[ni][1] = *(const f16x8*)(bp + swz1);
        }
#pragma unroll
        for (int mi = 0; mi < 2; mi++) {
            const char* ap = (const char*)As[cb] + (wr * 32 + mi * 16 + c) * 128;
            f16x8 a0 = *(const f16x8*)(ap + swz0);
            f16x8 a1 = *(const f16x8*)(ap + swz1);
#pragma unroll
            for (int ni = 0; ni < 4; ni++) {
                acc[mi][ni] = __builtin_amdgcn_mfma_f32_16x16x32_f16(a0, bF[ni][0], acc[mi][ni], 0, 0, 0);
                acc[mi][ni] = __builtin_amdgcn_mfma_f32_16x16x32_f16(a1, bF[ni][1], acc[mi][ni], 0, 0, 0);
            }
        }
        __syncthreads();
    }

#pragma unroll
    for (int mi = 0; mi < 2; mi++)
#pragma unroll
        for (int ni = 0; ni < 4; ni++)
#pragma unroll
            for (int r = 0; r < 4; r++) {
                int R  = tm * 64 + wr * 32 + mi * 16 + g * 4 + r;
                int Cc = tn * 128 + wc * 64 + ni * 16 + c;
                Cout[(size_t)R * E_ + Cc] = acc[mi][ni][r] + bias[Cc];
            }
}

// ---------------- flash attention: r19 + P LDS-bounce (4xb64 write, 2xb128 read) ----
// Grid 512 (8 xcd x 4 bh x 16 q-tiles of 64). Block 512 = 8 waves:
// ws = w>>2 (kv half), wq = w&3 (16-q subtile). LDS 80KB (K/V dbuf 64K + P 16K).
__global__ __launch_bounds__(512) void attn20_kernel(
    const _Float16* __restrict__ Qh,   // [B,H,LQ,D] pre-scaled by 0.125*log2e
    const _Float16* __restrict__ Kh,   // [B,H,LKV,D]
    const _Float16* __restrict__ Vt,   // [B*H][LKV/64][D][64] tiled
    const unsigned long long* __restrict__ Mbt,  // [32][B*LQ] transposed bitmask
    _Float16* __restrict__ O)          // [B,LQ,E] f16
{
    __shared__ __align__(16) char ldsraw[81920];  // [0,64K) K/V dbuf halves; [64K,80K) P per-wave

    const int bid0 = blockIdx.x;
    const int xcd = bid0 & 7, jj = bid0 >> 3;
    const int bh = xcd * 4 + (jj >> 4);
    const int qt = jj & 15;
    const int b = bh >> 4, h = bh & 15;
    const int tid = threadIdx.x;
    const int w = tid >> 6, lane = tid & 63;
    const int g = lane >> 4, c = lane & 15;
    const int ws = w >> 2, wq = w & 3;
    const int q0 = qt * 64 + wq * 16;

    char* half = ldsraw + ws * 32768;
    char* Pl   = ldsraw + 65536 + w * 2048;   // per-wave [q=c][kv 64] f16, slot-swizzled

    f16x8 qf[2];
#pragma unroll
    for (int ks = 0; ks < 2; ++ks)
        qf[ks] = *(const f16x8*)&Qh[((size_t)bh * LQ_ + q0 + c) * D_ + ks * 32 + g * 8];

    f32x4 o[4];
#pragma unroll
    for (int dt = 0; dt < 4; dt++) o[dt] = f32x4{0.f, 0.f, 0.f, 0.f};
    float m = -1e30f, lsum = 0.f;   // lsum = per-lane partial

    const int rowS = (lane >> 3);
    const int stOffBase = (rowS * 128) + (((lane & 7) ^ (rowS & 7)) * 16);
    const char* kTileB = (const char*)Kh + (size_t)bh * (LKV_ * D_ * 2) + (size_t)ws * 16 * 8192;
    const char* vTileB = (const char*)Vt + (size_t)bh * (LKV_ * D_ * 2) + (size_t)ws * 16 * 8192;

    int rdOff[2];
#pragma unroll
    for (int ks = 0; ks < 2; ++ks)
        rdOff[ks] = c * 128 + (((ks * 4 + g) ^ (c & 7)) * 16);

    // P LDS addresses (swizzle-consistent write/read)
    int pWr[4];
#pragma unroll
    for (int nt = 0; nt < 4; ++nt)
        pWr[nt] = c * 128 + (((nt * 2 + (g >> 1)) ^ (c & 7)) << 4) + ((g & 1) << 3);
    int pRd[2];
#pragma unroll
    for (int ks = 0; ks < 2; ++ks)
        pRd[ks] = c * 128 + (((ks * 4 + g) ^ (c & 7)) << 4);

    const int mRowIdx = b * LQ_ + q0 + c;
    const size_t mTile0 = (size_t)(ws * 16) * 2048 + mRowIdx;

    {
#pragma unroll
        for (int j = 0; j < 2; ++j) {
            gload16_lds(kTileB + (wq * 2048 + j * 1024) + stOffBase, half + (wq * 2048 + j * 1024));
            gload16_lds(vTileB + (wq * 2048 + j * 1024) + stOffBase, half + 8192 + (wq * 2048 + j * 1024));
        }
    }
    __syncthreads();

    for (int t = 0; t < 16; ++t) {
        if (t < 15) {
            const char* kt = kTileB + (size_t)(t + 1) * 8192;
            const char* vt = vTileB + (size_t)(t + 1) * 8192;
            char* dst = half + ((t + 1) & 1) * 16384;
#pragma unroll
            for (int j = 0; j < 2; ++j) {
                gload16_lds(kt + (wq * 2048 + j * 1024) + stOffBase, dst + (wq * 2048 + j * 1024));
                gload16_lds(vt + (wq * 2048 + j * 1024) + stOffBase, dst + 8192 + (wq * 2048 + j * 1024));
            }
        }

        const char* bufp = half + (t & 1) * 16384;

        f32x4 s[4];
#pragma unroll
        for (int nt = 0; nt < 4; ++nt) {
            f32x4 accS = f32x4{0.f, 0.f, 0.f, 0.f};
#pragma unroll
            for (int ks = 0; ks < 2; ++ks) {
                f16x8 kf = *(const f16x8*)(bufp + nt * 2048 + rdOff[ks]);
                accS = __builtin_amdgcn_mfma_f32_16x16x32_f16(kf, qf[ks], accS, 0, 0, 0);
            }
            s[nt] = accS;
        }
        unsigned long long mks = Mbt[mTile0 + (size_t)t * 2048] >> (g * 4);
#pragma unroll
        for (int nt = 0; nt < 4; ++nt) {
            unsigned nib = (unsigned)(mks >> (nt * 16)) & 0xFu;
            if (nib & 1u) s[nt][0] = -1e9f;
            if (nib & 2u) s[nt][1] = -1e9f;
            if (nib & 4u) s[nt][2] = -1e9f;
            if (nib & 8u) s[nt][3] = -1e9f;
        }
        // ---- lazy defer-max (r19-proven) ----
        float t0 = fmaxf(fmaxf(s[0][0], s[0][1]), fmaxf(s[0][2], s[0][3]));
        float t1 = fmaxf(fmaxf(s[1][0], s[1][1]), fmaxf(s[1][2], s[1][3]));
        float t2 = fmaxf(fmaxf(s[2][0], s[2][1]), fmaxf(s[2][2], s[2][3]));
        float t3 = fmaxf(fmaxf(s[3][0], s[3][1]), fmaxf(s[3][2], s[3][3]));
        float tmaxl = fmaxf(fmaxf(t0, t1), fmaxf(t2, t3));
        if (!__all(tmaxl - m <= 8.0f)) {
            float tq = fmaxf(tmaxl, __shfl_xor(tmaxl, 16, 64));
            tq = fmaxf(tq, __shfl_xor(tq, 32, 64));
            float mn = fmaxf(m, tq);
            float scl = exp2f(m - mn);
            m = mn;
            lsum *= scl;
#pragma unroll
            for (int dt = 0; dt < 4; dt++)
#pragma unroll
                for (int r = 0; r < 4; r++) o[dt][r] *= scl;
        }
        // ---- exp2 + per-lane lsum; pack P and write 4 x b64 to per-wave LDS ----
        float ts = 0.f;
#pragma unroll
        for (int nt = 0; nt < 4; ++nt) {
            float p0 = exp2f(s[nt][0] - m);
            float p1 = exp2f(s[nt][1] - m);
            float p2 = exp2f(s[nt][2] - m);
            float p3 = exp2f(s[nt][3] - m);
            ts += (p0 + p1) + (p2 + p3);
            uint2v pw;
            pw.x = __builtin_bit_cast(unsigned, __builtin_amdgcn_cvt_pkrtz(p0, p1));
            pw.y = __builtin_bit_cast(unsigned, __builtin_amdgcn_cvt_pkrtz(p2, p3));
            *(uint2v*)(Pl + pWr[nt]) = pw;    // rows nt*16+4g..+3 of col c
        }
        lsum += ts;
        // ---- PV: read P B-frag (2 x b128), V from LDS ----
#pragma unroll
        for (int ks = 0; ks < 2; ++ks) {
            f16x8 pf = *(const f16x8*)(Pl + pRd[ks]);
#pragma unroll
            for (int dt = 0; dt < 4; ++dt) {
                f16x8 vf = *(const f16x8*)(bufp + 8192 + dt * 2048 + rdOff[ks]);
                o[dt] = __builtin_amdgcn_mfma_f32_16x16x32_f16(vf, pf, o[dt], 0, 0, 0);
            }
        }
        __syncthreads();
    }

    // ---- final per-q lsum reduce ----
    lsum += __shfl_xor(lsum, 16, 64);
    lsum += __shfl_xor(lsum, 32, 64);

    float* OfP = (float*)ldsraw;                  // [128][68]
    float* Ml  = (float*)(ldsraw + 34816);        // [128][2]
#pragma unroll
    for (int dt = 0; dt < 4; ++dt)
#pragma unroll
        for (int r = 0; r < 4; r++)
            OfP[(w * 16 + c) * 68 + dt * 16 + 4 * g + r] = o[dt][r];
    if (lane < 16) {
        Ml[(w * 16 + lane) * 2 + 0] = m;
        Ml[(w * 16 + lane) * 2 + 1] = lsum;
    }
    __syncthreads();

    const int d = tid & 63;
    const int qlBase = tid >> 6;
#pragma unroll
    for (int pass = 0; pass < 8; ++pass) {
        int ql = pass * 8 + qlBase;          // 0..63
        float m0 = Ml[ql * 2], l0 = Ml[ql * 2 + 1];
        float m1 = Ml[(64 + ql) * 2], l1 = Ml[(64 + ql) * 2 + 1];
        float M  = fmaxf(m0, m1);
        float e0 = exp2f(m0 - M), e1 = exp2f(m1 - M);
        float L  = l0 * e0 + l1 * e1;
        float acc = OfP[ql * 68 + d] * e0 + OfP[(64 + ql) * 68 + d] * e1;
        O[((size_t)b * LQ_ + qt * 64 + ql) * E_ + h * 64 + d] = (_Float16)(acc / L);
    }
}

extern "C" void kernel_launch(void* const* d_in, const int* in_sizes, int n_in,
                              void* d_out, int out_size, void* d_ws, size_t ws_size,
                              hipStream_t stream)
{
    const float* x   = (const float*)d_in[0];
    const float* ctx = (const float*)d_in[1];
    const void*  msk = d_in[2];
    const float* Wq  = (const float*)d_in[3];
    const float* Wk  = (const float*)d_in[4];
    const float* Wv  = (const float*)d_in[5];
    const float* fcw = (const float*)d_in[6];
    const float* fcb = (const float*)d_in[7];
    float* out = (float*)d_out;

    char* ws = (char*)d_ws;
    size_t off = 0;
    auto alloc = [&](size_t bytes) { char* p = ws + off; off += (bytes + 255) & ~255ull; return p; };

    int* modep = (int*)alloc(256);
    unsigned long long* Mbt = (unsigned long long*)alloc((size_t)B_ * LQ_ * (LKV_ / 64) * 8);
    _Float16* xh   = (_Float16*)alloc((size_t)B_ * LQ_ * E_ * 2);
    _Float16* ch   = (_Float16*)alloc((size_t)B_ * LKV_ * E_ * 2);
    _Float16* wqh  = (_Float16*)alloc((size_t)E_ * E_ * 2);
    _Float16* wkvh = (_Float16*)alloc((size_t)2 * E_ * E_ * 2);
    _Float16* fwh  = (_Float16*)alloc((size_t)E_ * E_ * 2);
    float*    fbf  = (float*)alloc((size_t)E_ * 4);
    _Float16* Qh   = (_Float16*)alloc((size_t)B_ * H_ * LQ_ * D_ * 2);
    _Float16* Kh   = (_Float16*)alloc((size_t)B_ * H_ * LKV_ * D_ * 2);
    _Float16* Vt   = (_Float16*)alloc((size_t)B_ * H_ * LKV_ * D_ * 2);
    _Float16* Ob   = xh;  // safe alias: gemm20_qkv (last reader of xh) finishes before attn writes Ob
    (void)ws_size; (void)in_sizes; (void)n_in; (void)out_size;

    probe20<<<1, 64, 0, stream>>>(msk, modep);

    canon20_all<<<2048, 256, 0, stream>>>(x, ctx, Wq, Wk, Wv, fcw, fcb, msk,
                                          xh, ch, wqh, wkvh, fwh, fbf, Mbt, modep);

    gemm20_qkv<<<1280, 256, 0, stream>>>(xh, ch, wqh, wkvh, Qh, Kh, Vt);

    attn20_kernel<<<512, 512, 0, stream>>>(Qh, Kh, Vt, Mbt, Ob);

    gemm20_fc<<<256, 256, 0, stream>>>(Ob, fwh, fbf, out);
}

// Round 21
// 126.172 us; speedup vs baseline: 1.1808x; 1.0172x over previous
//
#include <hip/hip_runtime.h>
#include <hip/hip_bf16.h>

#define B_   2
#define H_   16
#define LQ_  1024
#define LKV_ 2048
#define D_   64
#define E_   1024

typedef __attribute__((ext_vector_type(8))) _Float16 f16x8;
typedef __attribute__((ext_vector_type(4))) float   f32x4;
typedef __attribute__((ext_vector_type(2))) unsigned uint2v;

__device__ __forceinline__ void gload16_lds(const void* g, void* l) {
    __builtin_amdgcn_global_load_lds(
        (const __attribute__((address_space(1))) unsigned int*)g,
        (__attribute__((address_space(3))) unsigned int*)l, 16, 0, 0);
}

// ---------------- one-wave mask-dtype probe ----------------
__global__ void probe21(const void* __restrict__ msk, int* __restrict__ modep) {
    int lane = threadIdx.x;
    int notInt = 0, notF32 = 0, notBF = 0;
    for (int i = lane; i < 256; i += 64) {
        unsigned v = ((const unsigned*)msk)[i * 997];
        if (v > 1u) notInt = 1;
        if (v != 0u && v != 0x3F800000u) notF32 = 1;
        if (v != 0u && v != 0x3F80u && v != 0x3F800000u && v != 0x3F803F80u) notBF = 1;
    }
    notInt = __any(notInt); notF32 = __any(notF32); notBF = __any(notBF);
    if (lane == 0) *modep = !notInt ? 0 : (!notF32 ? 1 : (!notBF ? 2 : 3));
}

// ---------------- streaming canonicalization (mask -> TRANSPOSED bits [t][row]) --------
__global__ void canon21_all(
    const float* __restrict__ x,  const float* __restrict__ ctx,
    const float* __restrict__ wq, const float* __restrict__ wk,
    const float* __restrict__ wv, const float* __restrict__ fw,
    const float* __restrict__ fb, const void* __restrict__ msk,
    _Float16* __restrict__ xh,  _Float16* __restrict__ ch,
    _Float16* __restrict__ wqh, _Float16* __restrict__ wkvh,
    _Float16* __restrict__ fwh, float* __restrict__ fbf,
    unsigned long long* __restrict__ Mbt, const int* __restrict__ modep)
{
    const int mmode = *modep;
    const int total = 1376384;
    const int stride = gridDim.x * blockDim.x;
    for (int idx = blockIdx.x * blockDim.x + threadIdx.x; idx < total; idx += stride) {
        if (idx < 1310720) {
            const float* src; _Float16* dst; int rel;
            if (idx < 262144)       { src = x;   dst = xh;   rel = idx; }
            else if (idx < 786432)  { src = ctx; dst = ch;   rel = idx - 262144; }
            else if (idx < 917504)  { src = wq;  dst = wqh;  rel = idx - 786432; }
            else if (idx < 1048576) { src = wk;  dst = wkvh; rel = idx - 917504; }
            else if (idx < 1179648) { src = wv;  dst = wkvh + (size_t)E_ * E_; rel = idx - 1048576; }
            else                    { src = fw;  dst = fwh;  rel = idx - 1179648; }
            f32x4 a = ((const f32x4*)src)[2 * rel], b = ((const f32x4*)src)[2 * rel + 1];
            f16x8 o;
            o[0] = (_Float16)a.x; o[1] = (_Float16)a.y; o[2] = (_Float16)a.z; o[3] = (_Float16)a.w;
            o[4] = (_Float16)b.x; o[5] = (_Float16)b.y; o[6] = (_Float16)b.z; o[7] = (_Float16)b.w;
            ((f16x8*)dst)[rel] = o;
        } else if (idx < 1310848) {
            int rel = idx - 1310720;
#pragma unroll
            for (int j = 0; j < 8; ++j) fbf[rel * 8 + j] = fb[rel * 8 + j];
        } else {
            int rel = idx - 1310848;           // rel = row*32 + t
            const size_t base = (size_t)rel * 64;
            unsigned long long v = 0;
            if (mmode == 0) {
                const int* p = (const int*)msk + base;
#pragma unroll
                for (int j = 0; j < 64; ++j) if (p[j] != 0) v |= 1ull << j;
            } else if (mmode == 1) {
                const float* p = (const float*)msk + base;
#pragma unroll
                for (int j = 0; j < 64; ++j) if (p[j] != 0.0f) v |= 1ull << j;
            } else if (mmode == 2) {
                const unsigned short* p = (const unsigned short*)msk + base;
#pragma unroll
                for (int j = 0; j < 64; ++j) if (p[j] != 0) v |= 1ull << j;
            } else {
                const unsigned char* p = (const unsigned char*)msk + base;
#pragma unroll
                for (int j = 0; j < 64; ++j) if (p[j] != 0) v |= 1ull << j;
            }
            Mbt[(rel & 31) * 2048 + (rel >> 5)] = v;   // transposed: [t][b*LQ+q]
        }
    }
}

// ---------------- fused Q + K|V projection GEMM: 64x128 tiles, BK=64, dbuf ----------
__global__ __launch_bounds__(256) void gemm21_qkv(
    const _Float16* __restrict__ xh, const _Float16* __restrict__ ch,
    const _Float16* __restrict__ wqh, const _Float16* __restrict__ wkvh,
    _Float16* __restrict__ Qh, _Float16* __restrict__ Kh, _Float16* __restrict__ Vt)
{
    __shared__ __align__(16) _Float16 As[2][64 * 64];    // 2 x 8KB
    __shared__ __align__(16) _Float16 Bs[2][128 * 64];   // 2 x 16KB

    const int bid = blockIdx.x;
    const bool isQ = bid < 256;
    const _Float16* A; const _Float16* W; int tm, tn;
    if (isQ) { A = xh; W = wqh; tm = bid >> 3; tn = bid & 7; }
    else     { int b2 = bid - 256; A = ch; W = wkvh; tm = b2 >> 4; tn = b2 & 15; }

    const int tid = threadIdx.x;
    const int w = tid >> 6, lane = tid & 63;
    const int g = lane >> 4, c = lane & 15;
    const int wr = w >> 1, wc = w & 1;
    const int rowS = lane >> 3, slot = lane & 7;
    const int stSwz = ((slot ^ (rowS & 7)) << 4);
    const int swz0 = ((g ^ (c & 7)) << 4);
    const int swz1 = (((4 + g) ^ (c & 7)) << 4);

    f32x4 acc[2][4];
#pragma unroll
    for (int i = 0; i < 2; i++)
#pragma unroll
        for (int j = 0; j < 4; j++) acc[i][j] = f32x4{0.f, 0.f, 0.f, 0.f};

    const size_t rowB = (size_t)E_ * 2;
    const char* gAbase = (const char*)A + (size_t)(tm * 64) * rowB;
    const char* gBbase = (const char*)W + (size_t)(tn * 128) * rowB;

#pragma unroll
    for (int j = 0; j < 2; ++j) {
        int rloc = w * 16 + j * 8 + rowS;
        gload16_lds(gAbase + (size_t)rloc * rowB + stSwz,
                    (char*)As[0] + (w * 16 + j * 8) * 128 + lane * 16);
    }
#pragma unroll
    for (int j = 0; j < 4; ++j) {
        int rloc = w * 32 + j * 8 + rowS;
        gload16_lds(gBbase + (size_t)rloc * rowB + stSwz,
                    (char*)Bs[0] + (w * 32 + j * 8) * 128 + lane * 16);
    }
    __syncthreads();

    for (int kt = 0; kt < 16; ++kt) {
        if (kt < 15) {
            const int nb = (kt + 1) & 1;
#pragma unroll
            for (int j = 0; j < 2; ++j) {
                int rloc = w * 16 + j * 8 + rowS;
                gload16_lds(gAbase + (size_t)rloc * rowB + (kt + 1) * 128 + stSwz,
                            (char*)As[nb] + (w * 16 + j * 8) * 128 + lane * 16);
            }
#pragma unroll
            for (int j = 0; j < 4; ++j) {
                int rloc = w * 32 + j * 8 + rowS;
                gload16_lds(gBbase + (size_t)rloc * rowB + (kt + 1) * 128 + stSwz,
                            (char*)Bs[nb] + (w * 32 + j * 8) * 128 + lane * 16);
            }
        }
        const int cb = kt & 1;

        f16x8 bF[4][2];
#pragma unroll
        for (int ni = 0; ni < 4; ni++) {
            const char* bp = (const char*)Bs[cb] + (wc * 64 + ni * 16 + c) * 128;
            bF[ni][0] = *(const f16x8*)(bp + swz0);
            bF[ni][1] = *(const f16x8*)(bp + swz1);
        }
#pragma unroll
        for (int mi = 0; mi < 2; mi++) {
            const char* ap = (const char*)As[cb] + (wr * 32 + mi * 16 + c) * 128;
            f16x8 a0 = *(const f16x8*)(ap + swz0);
            f16x8 a1 = *(const f16x8*)(ap + swz1);
#pragma unroll
            for (int ni = 0; ni < 4; ni++) {
                acc[mi][ni] = __builtin_amdgcn_mfma_f32_16x16x32_f16(a0, bF[ni][0], acc[mi][ni], 0, 0, 0);
                acc[mi][ni] = __builtin_amdgcn_mfma_f32_16x16x32_f16(a1, bF[ni][1], acc[mi][ni], 0, 0, 0);
            }
        }
        __syncthreads();
    }

#pragma unroll
    for (int mi = 0; mi < 2; mi++) {
#pragma unroll
        for (int ni = 0; ni < 4; ni++) {
#pragma unroll
            for (int r = 0; r < 4; r++) {
                int R  = tm * 64 + wr * 32 + mi * 16 + g * 4 + r;
                int Cc = tn * 128 + wc * 64 + ni * 16 + c;
                float v = acc[mi][ni][r];
                if (isQ) {
                    int b = R >> 10, q = R & 1023;
                    int h = Cc >> 6, d = Cc & 63;
                    // 0.125 * log2(e): attention works in exp2 domain
                    Qh[((size_t)(b * H_ + h) * LQ_ + q) * D_ + d] = (_Float16)(v * 0.18033688011112042f);
                } else {
                    int b = R >> 11, k = R & 2047;
                    int isV = Cc >> 10, cc2 = Cc & 1023;
                    int h = cc2 >> 6, d = cc2 & 63;
                    if (!isV)
                        Kh[((size_t)(b * H_ + h) * LKV_ + k) * D_ + d] = (_Float16)v;
                    else {
                        size_t bh = (size_t)(b * H_ + h);
                        Vt[((bh * (LKV_ / 64) + (k >> 6)) * D_ + d) * 64 + (k & 63)] = (_Float16)v;
                    }
                }
            }
        }
    }
}

// ---------------- FC GEMM: 64x128 tiles (256 blocks = 1/CU), BK=64, dbuf ------------
__global__ __launch_bounds__(256) void gemm21_fc(
    const _Float16* __restrict__ A, const _Float16* __restrict__ W,
    const float* __restrict__ bias, float* __restrict__ Cout)
{
    __shared__ __align__(16) _Float16 As[2][64 * 64];
    __shared__ __align__(16) _Float16 Bs[2][128 * 64];

    const int tm = blockIdx.x >> 3, tn = blockIdx.x & 7;   // 32 x 8
    const int tid = threadIdx.x;
    const int w = tid >> 6, lane = tid & 63;
    const int g = lane >> 4, c = lane & 15;
    const int wr = w >> 1, wc = w & 1;
    const int rowS = lane >> 3, slot = lane & 7;
    const int stSwz = ((slot ^ (rowS & 7)) << 4);
    const int swz0 = ((g ^ (c & 7)) << 4);
    const int swz1 = (((4 + g) ^ (c & 7)) << 4);

    f32x4 acc[2][4];
#pragma unroll
    for (int i = 0; i < 2; i++)
#pragma unroll
        for (int j = 0; j < 4; j++) acc[i][j] = f32x4{0.f, 0.f, 0.f, 0.f};

    const size_t rowB = (size_t)E_ * 2;
    const char* gAbase = (const char*)A + (size_t)(tm * 64) * rowB;
    const char* gBbase = (const char*)W + (size_t)(tn * 128) * rowB;

#pragma unroll
    for (int j = 0; j < 2; ++j) {
        int rloc = w * 16 + j * 8 + rowS;
        gload16_lds(gAbase + (size_t)rloc * rowB + stSwz,
                    (char*)As[0] + (w * 16 + j * 8) * 128 + lane * 16);
    }
#pragma unroll
    for (int j = 0; j < 4; ++j) {
        int rloc = w * 32 + j * 8 + rowS;
        gload16_lds(gBbase + (size_t)rloc * rowB + stSwz,
                    (char*)Bs[0] + (w * 32 + j * 8) * 128 + lane * 16);
    }
    __syncthreads();

    for (int kt = 0; kt < 16; ++kt) {
        if (kt < 15) {
            const int nb = (kt + 1) & 1;
#pragma unroll
            for (int j = 0; j < 2; ++j) {
                int rloc = w * 16 + j * 8 + rowS;
                gload16_lds(gAbase + (size_t)rloc * rowB + (kt + 1) * 128 + stSwz,
                            (char*)As[nb] + (w * 16 + j * 8) * 128 + lane * 16);
            }
#pragma unroll
            for (int j = 0; j < 4; ++j) {
                int rloc = w * 32 + j * 8 + rowS;
                gload16_lds(gBbase + (size_t)rloc * rowB + (kt + 1) * 128 + stSwz,
                            (char*)Bs[nb] + (w * 32 + j * 8) * 128 + lane * 16);
            }
        }
        const int cb = kt & 1;

        f16x8 bF[4][2];
#pragma unroll
        for (int ni = 0; ni < 4; ni++) {
            const char* bp = (const char*)Bs[cb] + (wc * 64 + ni * 16 + c) * 128;
            bF[ni][0] = *(const f16x8*)(bp + swz0);
            bF[ni][1] = *(const f16x8*)(bp + swz1);
        }
#pragma unroll
        for (int mi = 0; mi < 2; mi++) {
            const char* ap = (const char*)As[cb] + (wr * 32 + mi * 16 + c) * 128;
            f16x8 a0 = *(const f16x8*)(ap + swz0);
            f16x8 a1 = *(const f16x8*)(ap + swz1);
#pragma unroll
            for (int ni = 0; ni < 4; ni++) {
                acc[mi][ni] = __builtin_amdgcn_mfma_f32_16x16x32_f16(a0, bF[ni][0], acc[mi][ni], 0, 0, 0);
                acc[mi][ni] = __builtin_amdgcn_mfma_f32_16x16x32_f16(a1, bF[ni][1], acc[mi][ni], 0, 0, 0);
            }
        }
        __syncthreads();
    }

#pragma unroll
    for (int mi = 0; mi < 2; mi++)
#pragma unroll
        for (int ni = 0; ni < 4; ni++)
#pragma unroll
            for (int r = 0; r < 4; r++) {
                int R  = tm * 64 + wr * 32 + mi * 16 + g * 4 + r;
                int Cc = tn * 128 + wc * 64 + ni * 16 + c;
                Cout[(size_t)R * E_ + Cc] = acc[mi][ni][r] + bias[Cc];
            }
}

// ---------------- flash attention: r20 + T5 setprio + mask register-prefetch --------
// Grid 512 (8 xcd x 4 bh x 16 q-tiles of 64). Block 512 = 8 waves:
// ws = w>>2 (kv half), wq = w&3 (16-q subtile). LDS 80KB.
__global__ __launch_bounds__(512) void attn21_kernel(
    const _Float16* __restrict__ Qh,   // [B,H,LQ,D] pre-scaled by 0.125*log2e
    const _Float16* __restrict__ Kh,   // [B,H,LKV,D]
    const _Float16* __restrict__ Vt,   // [B*H][LKV/64][D][64] tiled
    const unsigned long long* __restrict__ Mbt,  // [32][B*LQ] transposed bitmask
    _Float16* __restrict__ O)          // [B,LQ,E] f16
{
    __shared__ __align__(16) char ldsraw[81920];  // [0,64K) K/V dbuf halves; [64K,80K) P per-wave

    const int bid0 = blockIdx.x;
    const int xcd = bid0 & 7, jj = bid0 >> 3;
    const int bh = xcd * 4 + (jj >> 4);
    const int qt = jj & 15;
    const int b = bh >> 4, h = bh & 15;
    const int tid = threadIdx.x;
    const int w = tid >> 6, lane = tid & 63;
    const int g = lane >> 4, c = lane & 15;
    const int ws = w >> 2, wq = w & 3;
    const int q0 = qt * 64 + wq * 16;

    char* half = ldsraw + ws * 32768;
    char* Pl   = ldsraw + 65536 + w * 2048;   // per-wave [q=c][kv 64] f16, slot-swizzled

    f16x8 qf[2];
#pragma unroll
    for (int ks = 0; ks < 2; ++ks)
        qf[ks] = *(const f16x8*)&Qh[((size_t)bh * LQ_ + q0 + c) * D_ + ks * 32 + g * 8];

    f32x4 o[4];
#pragma unroll
    for (int dt = 0; dt < 4; dt++) o[dt] = f32x4{0.f, 0.f, 0.f, 0.f};
    float m = -1e30f, lsum = 0.f;   // lsum = per-lane partial

    const int rowS = (lane >> 3);
    const int stOffBase = (rowS * 128) + (((lane & 7) ^ (rowS & 7)) * 16);
    const char* kTileB = (const char*)Kh + (size_t)bh * (LKV_ * D_ * 2) + (size_t)ws * 16 * 8192;
    const char* vTileB = (const char*)Vt + (size_t)bh * (LKV_ * D_ * 2) + (size_t)ws * 16 * 8192;

    int rdOff[2];
#pragma unroll
    for (int ks = 0; ks < 2; ++ks)
        rdOff[ks] = c * 128 + (((ks * 4 + g) ^ (c & 7)) * 16);

    int pWr[4];
#pragma unroll
    for (int nt = 0; nt < 4; ++nt)
        pWr[nt] = c * 128 + (((nt * 2 + (g >> 1)) ^ (c & 7)) << 4) + ((g & 1) << 3);
    int pRd[2];
#pragma unroll
    for (int ks = 0; ks < 2; ++ks)
        pRd[ks] = c * 128 + (((ks * 4 + g) ^ (c & 7)) << 4);

    const int mRowIdx = b * LQ_ + q0 + c;
    const size_t mTile0 = (size_t)(ws * 16) * 2048 + mRowIdx;

    {
#pragma unroll
        for (int j = 0; j < 2; ++j) {
            gload16_lds(kTileB + (wq * 2048 + j * 1024) + stOffBase, half + (wq * 2048 + j * 1024));
            gload16_lds(vTileB + (wq * 2048 + j * 1024) + stOffBase, half + 8192 + (wq * 2048 + j * 1024));
        }
    }
    unsigned long long mksCur = Mbt[mTile0];       // mask for tile 0 (prefetched)
    __syncthreads();

    for (int t = 0; t < 16; ++t) {
        unsigned long long mksNext = 0;
        if (t < 15) {
            const char* kt = kTileB + (size_t)(t + 1) * 8192;
            const char* vt = vTileB + (size_t)(t + 1) * 8192;
            char* dst = half + ((t + 1) & 1) * 16384;
#pragma unroll
            for (int j = 0; j < 2; ++j) {
                gload16_lds(kt + (wq * 2048 + j * 1024) + stOffBase, dst + (wq * 2048 + j * 1024));
                gload16_lds(vt + (wq * 2048 + j * 1024) + stOffBase, dst + 8192 + (wq * 2048 + j * 1024));
            }
            mksNext = Mbt[mTile0 + (size_t)(t + 1) * 2048];   // hide L2 latency under QK^T
        }

        const char* bufp = half + (t & 1) * 16384;

        f32x4 s[4];
        __builtin_amdgcn_s_setprio(1);
#pragma unroll
        for (int nt = 0; nt < 4; ++nt) {
            f32x4 accS = f32x4{0.f, 0.f, 0.f, 0.f};
#pragma unroll
            for (int ks = 0; ks < 2; ++ks) {
                f16x8 kf = *(const f16x8*)(bufp + nt * 2048 + rdOff[ks]);
                accS = __builtin_amdgcn_mfma_f32_16x16x32_f16(kf, qf[ks], accS, 0, 0, 0);
            }
            s[nt] = accS;
        }
        __builtin_amdgcn_s_setprio(0);

        unsigned long long mks = mksCur >> (g * 4);
#pragma unroll
        for (int nt = 0; nt < 4; ++nt) {
            unsigned nib = (unsigned)(mks >> (nt * 16)) & 0xFu;
            if (nib & 1u) s[nt][0] = -1e9f;
            if (nib & 2u) s[nt][1] = -1e9f;
            if (nib & 4u) s[nt][2] = -1e9f;
            if (nib & 8u) s[nt][3] = -1e9f;
        }
        // ---- lazy defer-max (r19-proven) ----
        float t0 = fmaxf(fmaxf(s[0][0], s[0][1]), fmaxf(s[0][2], s[0][3]));
        float t1 = fmaxf(fmaxf(s[1][0], s[1][1]), fmaxf(s[1][2], s[1][3]));
        float t2 = fmaxf(fmaxf(s[2][0], s[2][1]), fmaxf(s[2][2], s[2][3]));
        float t3 = fmaxf(fmaxf(s[3][0], s[3][1]), fmaxf(s[3][2], s[3][3]));
        float tmaxl = fmaxf(fmaxf(t0, t1), fmaxf(t2, t3));
        if (!__all(tmaxl - m <= 8.0f)) {
            float tq = fmaxf(tmaxl, __shfl_xor(tmaxl, 16, 64));
            tq = fmaxf(tq, __shfl_xor(tq, 32, 64));
            float mn = fmaxf(m, tq);
            float scl = exp2f(m - mn);
            m = mn;
            lsum *= scl;
#pragma unroll
            for (int dt = 0; dt < 4; dt++)
#pragma unroll
                for (int r = 0; r < 4; r++) o[dt][r] *= scl;
        }
        // ---- exp2 + per-lane lsum; pack P and write 4 x b64 to per-wave LDS ----
        float ts = 0.f;
#pragma unroll
        for (int nt = 0; nt < 4; ++nt) {
            float p0 = exp2f(s[nt][0] - m);
            float p1 = exp2f(s[nt][1] - m);
            float p2 = exp2f(s[nt][2] - m);
            float p3 = exp2f(s[nt][3] - m);
            ts += (p0 + p1) + (p2 + p3);
            uint2v pw;
            pw.x = __builtin_bit_cast(unsigned, __builtin_amdgcn_cvt_pkrtz(p0, p1));
            pw.y = __builtin_bit_cast(unsigned, __builtin_amdgcn_cvt_pkrtz(p2, p3));
            *(uint2v*)(Pl + pWr[nt]) = pw;    // rows nt*16+4g..+3 of col c
        }
        lsum += ts;
        // ---- PV: read P B-frag (2 x b128), V from LDS ----
        __builtin_amdgcn_s_setprio(1);
#pragma unroll
        for (int ks = 0; ks < 2; ++ks) {
            f16x8 pf = *(const f16x8*)(Pl + pRd[ks]);
#pragma unroll
            for (int dt = 0; dt < 4; ++dt) {
                f16x8 vf = *(const f16x8*)(bufp + 8192 + dt * 2048 + rdOff[ks]);
                o[dt] = __builtin_amdgcn_mfma_f32_16x16x32_f16(vf, pf, o[dt], 0, 0, 0);
            }
        }
        __builtin_amdgcn_s_setprio(0);
        __syncthreads();
        mksCur = mksNext;
    }

    // ---- final per-q lsum reduce ----
    lsum += __shfl_xor(lsum, 16, 64);
    lsum += __shfl_xor(lsum, 32, 64);

    float* OfP = (float*)ldsraw;                  // [128][68]
    float* Ml  = (float*)(ldsraw + 34816);        // [128][2]
#pragma unroll
    for (int dt = 0; dt < 4; ++dt)
#pragma unroll
        for (int r = 0; r < 4; r++)
            OfP[(w * 16 + c) * 68 + dt * 16 + 4 * g + r] = o[dt][r];
    if (lane < 16) {
        Ml[(w * 16 + lane) * 2 + 0] = m;
        Ml[(w * 16 + lane) * 2 + 1] = lsum;
    }
    __syncthreads();

    const int d = tid & 63;
    const int qlBase = tid >> 6;
#pragma unroll
    for (int pass = 0; pass < 8; ++pass) {
        int ql = pass * 8 + qlBase;          // 0..63
        float m0 = Ml[ql * 2], l0 = Ml[ql * 2 + 1];
        float m1 = Ml[(64 + ql) * 2], l1 = Ml[(64 + ql) * 2 + 1];
        float M  = fmaxf(m0, m1);
        float e0 = exp2f(m0 - M), e1 = exp2f(m1 - M);
        float L  = l0 * e0 + l1 * e1;
        float acc = OfP[ql * 68 + d] * e0 + OfP[(64 + ql) * 68 + d] * e1;
        O[((size_t)b * LQ_ + qt * 64 + ql) * E_ + h * 64 + d] = (_Float16)(acc / L);
    }
}

extern "C" void kernel_launch(void* const* d_in, const int* in_sizes, int n_in,
                              void* d_out, int out_size, void* d_ws, size_t ws_size,
                              hipStream_t stream)
{
    const float* x   = (const float*)d_in[0];
    const float* ctx = (const float*)d_in[1];
    const void*  msk = d_in[2];
    const float* Wq  = (const float*)d_in[3];
    const float* Wk  = (const float*)d_in[4];
    const float* Wv  = (const float*)d_in[5];
    const float* fcw = (const float*)d_in[6];
    const float* fcb = (const float*)d_in[7];
    float* out = (float*)d_out;

    char* ws = (char*)d_ws;
    size_t off = 0;
    auto alloc = [&](size_t bytes) { char* p = ws + off; off += (bytes + 255) & ~255ull; return p; };

    int* modep = (int*)alloc(256);
    unsigned long long* Mbt = (unsigned long long*)alloc((size_t)B_ * LQ_ * (LKV_ / 64) * 8);
    _Float16* xh   = (_Float16*)alloc((size_t)B_ * LQ_ * E_ * 2);
    _Float16* ch   = (_Float16*)alloc((size_t)B_ * LKV_ * E_ * 2);
    _Float16* wqh  = (_Float16*)alloc((size_t)E_ * E_ * 2);
    _Float16* wkvh = (_Float16*)alloc((size_t)2 * E_ * E_ * 2);
    _Float16* fwh  = (_Float16*)alloc((size_t)E_ * E_ * 2);
    float*    fbf  = (float*)alloc((size_t)E_ * 4);
    _Float16* Qh   = (_Float16*)alloc((size_t)B_ * H_ * LQ_ * D_ * 2);
    _Float16* Kh   = (_Float16*)alloc((size_t)B_ * H_ * LKV_ * D_ * 2);
    _Float16* Vt   = (_Float16*)alloc((size_t)B_ * H_ * LKV_ * D_ * 2);
    _Float16* Ob   = xh;  // safe alias: gemm21_qkv (last reader of xh) finishes before attn writes Ob
    (void)ws_size; (void)in_sizes; (void)n_in; (void)out_size;

    probe21<<<1, 64, 0, stream>>>(msk, modep);

    canon21_all<<<2048, 256, 0, stream>>>(x, ctx, Wq, Wk, Wv, fcw, fcb, msk,
                                          xh, ch, wqh, wkvh, fwh, fbf, Mbt, modep);

    gemm21_qkv<<<1280, 256, 0, stream>>>(xh, ch, wqh, wkvh, Qh, Kh, Vt);

    attn21_kernel<<<512, 512, 0, stream>>>(Qh, Kh, Vt, Mbt, Ob);

    gemm21_fc<<<256, 256, 0, stream>>>(Ob, fwh, fbf, out);
}

// Round 22
// 124.755 us; speedup vs baseline: 1.1942x; 1.0114x over previous
//
#include <hip/hip_runtime.h>
#include <hip/hip_bf16.h>

#define B_   2
#define H_   16
#define LQ_  1024
#define LKV_ 2048
#define D_   64
#define E_   1024

typedef __attribute__((ext_vector_type(8))) _Float16 f16x8;
typedef __attribute__((ext_vector_type(4))) float   f32x4;
typedef __attribute__((ext_vector_type(2))) unsigned uint2v;

__device__ __forceinline__ void gload16_lds(const void* g, void* l) {
    __builtin_amdgcn_global_load_lds(
        (const __attribute__((address_space(1))) unsigned int*)g,
        (__attribute__((address_space(3))) unsigned int*)l, 16, 0, 0);
}

// ---------------- one-wave mask-dtype probe ----------------
__global__ void probe22(const void* __restrict__ msk, int* __restrict__ modep) {
    int lane = threadIdx.x;
    int notInt = 0, notF32 = 0, notBF = 0;
    for (int i = lane; i < 256; i += 64) {
        unsigned v = ((const unsigned*)msk)[i * 997];
        if (v > 1u) notInt = 1;
        if (v != 0u && v != 0x3F800000u) notF32 = 1;
        if (v != 0u && v != 0x3F80u && v != 0x3F800000u && v != 0x3F803F80u) notBF = 1;
    }
    notInt = __any(notInt); notF32 = __any(notF32); notBF = __any(notBF);
    if (lane == 0) *modep = !notInt ? 0 : (!notF32 ? 1 : (!notBF ? 2 : 3));
}

// ---------------- streaming canonicalization (mask -> TRANSPOSED bits [t][row]) --------
__global__ void canon22_all(
    const float* __restrict__ x,  const float* __restrict__ ctx,
    const float* __restrict__ wq, const float* __restrict__ wk,
    const float* __restrict__ wv, const float* __restrict__ fw,
    const float* __restrict__ fb, const void* __restrict__ msk,
    _Float16* __restrict__ xh,  _Float16* __restrict__ ch,
    _Float16* __restrict__ wqh, _Float16* __restrict__ wkvh,
    _Float16* __restrict__ fwh, float* __restrict__ fbf,
    unsigned long long* __restrict__ Mbt, const int* __restrict__ modep)
{
    const int mmode = *modep;
    const int total = 1376384;
    const int stride = gridDim.x * blockDim.x;
    for (int idx = blockIdx.x * blockDim.x + threadIdx.x; idx < total; idx += stride) {
        if (idx < 1310720) {
            const float* src; _Float16* dst; int rel;
            if (idx < 262144)       { src = x;   dst = xh;   rel = idx; }
            else if (idx < 786432)  { src = ctx; dst = ch;   rel = idx - 262144; }
            else if (idx < 917504)  { src = wq;  dst = wqh;  rel = idx - 786432; }
            else if (idx < 1048576) { src = wk;  dst = wkvh; rel = idx - 917504; }
            else if (idx < 1179648) { src = wv;  dst = wkvh + (size_t)E_ * E_; rel = idx - 1048576; }
            else                    { src = fw;  dst = fwh;  rel = idx - 1179648; }
            f32x4 a = ((const f32x4*)src)[2 * rel], b = ((const f32x4*)src)[2 * rel + 1];
            f16x8 o;
            o[0] = (_Float16)a.x; o[1] = (_Float16)a.y; o[2] = (_Float16)a.z; o[3] = (_Float16)a.w;
            o[4] = (_Float16)b.x; o[5] = (_Float16)b.y; o[6] = (_Float16)b.z; o[7] = (_Float16)b.w;
            ((f16x8*)dst)[rel] = o;
        } else if (idx < 1310848) {
            int rel = idx - 1310720;
#pragma unroll
            for (int j = 0; j < 8; ++j) fbf[rel * 8 + j] = fb[rel * 8 + j];
        } else {
            int rel = idx - 1310848;           // rel = row*32 + t
            const size_t base = (size_t)rel * 64;
            unsigned long long v = 0;
            if (mmode == 0) {
                const int* p = (const int*)msk + base;
#pragma unroll
                for (int j = 0; j < 64; ++j) if (p[j] != 0) v |= 1ull << j;
            } else if (mmode == 1) {
                const float* p = (const float*)msk + base;
#pragma unroll
                for (int j = 0; j < 64; ++j) if (p[j] != 0.0f) v |= 1ull << j;
            } else if (mmode == 2) {
                const unsigned short* p = (const unsigned short*)msk + base;
#pragma unroll
                for (int j = 0; j < 64; ++j) if (p[j] != 0) v |= 1ull << j;
            } else {
                const unsigned char* p = (const unsigned char*)msk + base;
#pragma unroll
                for (int j = 0; j < 64; ++j) if (p[j] != 0) v |= 1ull << j;
            }
            Mbt[(rel & 31) * 2048 + (rel >> 5)] = v;   // transposed: [t][b*LQ+q]
        }
    }
}

// ---------------- fused Q + K|V projection GEMM: 64x128 tiles, BK=64, dbuf ----------
// XCD-aware block mapping: bid%8 is a function of tm ONLY, so all tn-blocks
// sharing an A-panel land on one XCD (A re-reads become L2 hits).
//   Q  (bid <  256): tm = bid & 31,  tn = bid >> 5   (bid = tn*32 + tm, 32%8==0)
//   KV (bid >= 256): b2 = bid-256; tm = b2 & 63, tn = b2 >> 6  (b2 = tn*64 + tm)
__global__ __launch_bounds__(256) void gemm22_qkv(
    const _Float16* __restrict__ xh, const _Float16* __restrict__ ch,
    const _Float16* __restrict__ wqh, const _Float16* __restrict__ wkvh,
    _Float16* __restrict__ Qh, _Float16* __restrict__ Kh, _Float16* __restrict__ Vt)
{
    __shared__ __align__(16) _Float16 As[2][64 * 64];    // 2 x 8KB
    __shared__ __align__(16) _Float16 Bs[2][128 * 64];   // 2 x 16KB

    const int bid = blockIdx.x;
    const bool isQ = bid < 256;
    const _Float16* A; const _Float16* W; int tm, tn;
    if (isQ) { A = xh; W = wqh; tm = bid & 31; tn = bid >> 5; }
    else     { int b2 = bid - 256; A = ch; W = wkvh; tm = b2 & 63; tn = b2 >> 6; }

    const int tid = threadIdx.x;
    const int w = tid >> 6, lane = tid & 63;
    const int g = lane >> 4, c = lane & 15;
    const int wr = w >> 1, wc = w & 1;
    const int rowS = lane >> 3, slot = lane & 7;
    const int stSwz = ((slot ^ (rowS & 7)) << 4);
    const int swz0 = ((g ^ (c & 7)) << 4);
    const int swz1 = (((4 + g) ^ (c & 7)) << 4);

    f32x4 acc[2][4];
#pragma unroll
    for (int i = 0; i < 2; i++)
#pragma unroll
        for (int j = 0; j < 4; j++) acc[i][j] = f32x4{0.f, 0.f, 0.f, 0.f};

    const size_t rowB = (size_t)E_ * 2;
    const char* gAbase = (const char*)A + (size_t)(tm * 64) * rowB;
    const char* gBbase = (const char*)W + (size_t)(tn * 128) * rowB;

#pragma unroll
    for (int j = 0; j < 2; ++j) {
        int rloc = w * 16 + j * 8 + rowS;
        gload16_lds(gAbase + (size_t)rloc * rowB + stSwz,
                    (char*)As[0] + (w * 16 + j * 8) * 128 + lane * 16);
    }
#pragma unroll
    for (int j = 0; j < 4; ++j) {
        int rloc = w * 32 + j * 8 + rowS;
        gload16_lds(gBbase + (size_t)rloc * rowB + stSwz,
                    (char*)Bs[0] + (w * 32 + j * 8) * 128 + lane * 16);
    }
    __syncthreads();

    for (int kt = 0; kt < 16; ++kt) {
        if (kt < 15) {
            const int nb = (kt + 1) & 1;
#pragma unroll
            for (int j = 0; j < 2; ++j) {
                int rloc = w * 16 + j * 8 + rowS;
                gload16_lds(gAbase + (size_t)rloc * rowB + (kt + 1) * 128 + stSwz,
                            (char*)As[nb] + (w * 16 + j * 8) * 128 + lane * 16);
            }
#pragma unroll
            for (int j = 0; j < 4; ++j) {
                int rloc = w * 32 + j * 8 + rowS;
                gload16_lds(gBbase + (size_t)rloc * rowB + (kt + 1) * 128 + stSwz,
                            (char*)Bs[nb] + (w * 32 + j * 8) * 128 + lane * 16);
            }
        }
        const int cb = kt & 1;

        f16x8 bF[4][2];
#pragma unroll
        for (int ni = 0; ni < 4; ni++) {
            const char* bp = (const char*)Bs[cb] + (wc * 64 + ni * 16 + c) * 128;
            bF[ni][0] = *(const f16x8*)(bp + swz0);
            bF[ni][1] = *(const f16x8*)(bp + swz1);
        }
#pragma unroll
        for (int mi = 0; mi < 2; mi++) {
            const char* ap = (const char*)As[cb] + (wr * 32 + mi * 16 + c) * 128;
            f16x8 a0 = *(const f16x8*)(ap + swz0);
            f16x8 a1 = *(const f16x8*)(ap + swz1);
#pragma unroll
            for (int ni = 0; ni < 4; ni++) {
                acc[mi][ni] = __builtin_amdgcn_mfma_f32_16x16x32_f16(a0, bF[ni][0], acc[mi][ni], 0, 0, 0);
                acc[mi][ni] = __builtin_amdgcn_mfma_f32_16x16x32_f16(a1, bF[ni][1], acc[mi][ni], 0, 0, 0);
            }
        }
        __syncthreads();
    }

#pragma unroll
    for (int mi = 0; mi < 2; mi++) {
#pragma unroll
        for (int ni = 0; ni < 4; ni++) {
#pragma unroll
            for (int r = 0; r < 4; r++) {
                int R  = tm * 64 + wr * 32 + mi * 16 + g * 4 + r;
                int Cc = tn * 128 + wc * 64 + ni * 16 + c;
                float v = acc[mi][ni][r];
                if (isQ) {
                    int b = R >> 10, q = R & 1023;
                    int h = Cc >> 6, d = Cc & 63;
                    // 0.125 * log2(e): attention works in exp2 domain
                    Qh[((size_t)(b * H_ + h) * LQ_ + q) * D_ + d] = (_Float16)(v * 0.18033688011112042f);
                } else {
                    int b = R >> 11, k = R & 2047;
                    int isV = Cc >> 10, cc2 = Cc & 1023;
                    int h = cc2 >> 6, d = cc2 & 63;
                    if (!isV)
                        Kh[((size_t)(b * H_ + h) * LKV_ + k) * D_ + d] = (_Float16)v;
                    else {
                        size_t bh = (size_t)(b * H_ + h);
                        Vt[((bh * (LKV_ / 64) + (k >> 6)) * D_ + d) * 64 + (k & 63)] = (_Float16)v;
                    }
                }
            }
        }
    }
}

// ---------------- FC GEMM: 64x128 tiles, XCD-aware mapping, BK=64, dbuf ------------
__global__ __launch_bounds__(256) void gemm22_fc(
    const _Float16* __restrict__ A, const _Float16* __restrict__ W,
    const float* __restrict__ bias, float* __restrict__ Cout)
{
    __shared__ __align__(16) _Float16 As[2][64 * 64];
    __shared__ __align__(16) _Float16 Bs[2][128 * 64];

    const int tm = blockIdx.x & 31, tn = blockIdx.x >> 5;   // bid = tn*32 + tm
    const int tid = threadIdx.x;
    const int w = tid >> 6, lane = tid & 63;
    const int g = lane >> 4, c = lane & 15;
    const int wr = w >> 1, wc = w & 1;
    const int rowS = lane >> 3, slot = lane & 7;
    const int stSwz = ((slot ^ (rowS & 7)) << 4);
    const int swz0 = ((g ^ (c & 7)) << 4);
    const int swz1 = (((4 + g) ^ (c & 7)) << 4);

    f32x4 acc[2][4];
#pragma unroll
    for (int i = 0; i < 2; i++)
#pragma unroll
        for (int j = 0; j < 4; j++) acc[i][j] = f32x4{0.f, 0.f, 0.f, 0.f};

    const size_t rowB = (size_t)E_ * 2;
    const char* gAbase = (const char*)A + (size_t)(tm * 64) * rowB;
    const char* gBbase = (const char*)W + (size_t)(tn * 128) * rowB;

#pragma unroll
    for (int j = 0; j < 2; ++j) {
        int rloc = w * 16 + j * 8 + rowS;
        gload16_lds(gAbase + (size_t)rloc * rowB + stSwz,
                    (char*)As[0] + (w * 16 + j * 8) * 128 + lane * 16);
    }
#pragma unroll
    for (int j = 0; j < 4; ++j) {
        int rloc = w * 32 + j * 8 + rowS;
        gload16_lds(gBbase + (size_t)rloc * rowB + stSwz,
                    (char*)Bs[0] + (w * 32 + j * 8) * 128 + lane * 16);
    }
    __syncthreads();

    for (int kt = 0; kt < 16; ++kt) {
        if (kt < 15) {
            const int nb = (kt + 1) & 1;
#pragma unroll
            for (int j = 0; j < 2; ++j) {
                int rloc = w * 16 + j * 8 + rowS;
                gload16_lds(gAbase + (size_t)rloc * rowB + (kt + 1) * 128 + stSwz,
                            (char*)As[nb] + (w * 16 + j * 8) * 128 + lane * 16);
            }
#pragma unroll
            for (int j = 0; j < 4; ++j) {
                int rloc = w * 32 + j * 8 + rowS;
                gload16_lds(gBbase + (size_t)rloc * rowB + (kt + 1) * 128 + stSwz,
                            (char*)Bs[nb] + (w * 32 + j * 8) * 128 + lane * 16);
            }
        }
        const int cb = kt & 1;

        f16x8 bF[4][2];
#pragma unroll
        for (int ni = 0; ni < 4; ni++) {
            const char* bp = (const char*)Bs[cb] + (wc * 64 + ni * 16 + c) * 128;
            bF[ni][0] = *(const f16x8*)(bp + swz0);
            bF[ni][1] = *(const f16x8*)(bp + swz1);
        }
#pragma unroll
        for (int mi = 0; mi < 2; mi++) {
            const char* ap = (const char*)As[cb] + (wr * 32 + mi * 16 + c) * 128;
            f16x8 a0 = *(const f16x8*)(ap + swz0);
            f16x8 a1 = *(const f16x8*)(ap + swz1);
#pragma unroll
            for (int ni = 0; ni < 4; ni++) {
                acc[mi][ni] = __builtin_amdgcn_mfma_f32_16x16x32_f16(a0, bF[ni][0], acc[mi][ni], 0, 0, 0);
                acc[mi][ni] = __builtin_amdgcn_mfma_f32_16x16x32_f16(a1, bF[ni][1], acc[mi][ni], 0, 0, 0);
            }
        }
        __syncthreads();
    }

#pragma unroll
    for (int mi = 0; mi < 2; mi++)
#pragma unroll
        for (int ni = 0; ni < 4; ni++)
#pragma unroll
            for (int r = 0; r < 4; r++) {
                int R  = tm * 64 + wr * 32 + mi * 16 + g * 4 + r;
                int Cc = tn * 128 + wc * 64 + ni * 16 + c;
                Cout[(size_t)R * E_ + Cc] = acc[mi][ni][r] + bias[Cc];
            }
}

// ---------------- flash attention: r21 champion, verbatim ----------------
__global__ __launch_bounds__(512) void attn22_kernel(
    const _Float16* __restrict__ Qh,   // [B,H,LQ,D] pre-scaled by 0.125*log2e
    const _Float16* __restrict__ Kh,   // [B,H,LKV,D]
    const _Float16* __restrict__ Vt,   // [B*H][LKV/64][D][64] tiled
    const unsigned long long* __restrict__ Mbt,  // [32][B*LQ] transposed bitmask
    _Float16* __restrict__ O)          // [B,LQ,E] f16
{
    __shared__ __align__(16) char ldsraw[81920];  // [0,64K) K/V dbuf halves; [64K,80K) P per-wave

    const int bid0 = blockIdx.x;
    const int xcd = bid0 & 7, jj = bid0 >> 3;
    const int bh = xcd * 4 + (jj >> 4);
    const int qt = jj & 15;
    const int b = bh >> 4, h = bh & 15;
    const int tid = threadIdx.x;
    const int w = tid >> 6, lane = tid & 63;
    const int g = lane >> 4, c = lane & 15;
    const int ws = w >> 2, wq = w & 3;
    const int q0 = qt * 64 + wq * 16;

    char* half = ldsraw + ws * 32768;
    char* Pl   = ldsraw + 65536 + w * 2048;   // per-wave [q=c][kv 64] f16, slot-swizzled

    f16x8 qf[2];
#pragma unroll
    for (int ks = 0; ks < 2; ++ks)
        qf[ks] = *(const f16x8*)&Qh[((size_t)bh * LQ_ + q0 + c) * D_ + ks * 32 + g * 8];

    f32x4 o[4];
#pragma unroll
    for (int dt = 0; dt < 4; dt++) o[dt] = f32x4{0.f, 0.f, 0.f, 0.f};
    float m = -1e30f, lsum = 0.f;   // lsum = per-lane partial

    const int rowS = (lane >> 3);
    const int stOffBase = (rowS * 128) + (((lane & 7) ^ (rowS & 7)) * 16);
    const char* kTileB = (const char*)Kh + (size_t)bh * (LKV_ * D_ * 2) + (size_t)ws * 16 * 8192;
    const char* vTileB = (const char*)Vt + (size_t)bh * (LKV_ * D_ * 2) + (size_t)ws * 16 * 8192;

    int rdOff[2];
#pragma unroll
    for (int ks = 0; ks < 2; ++ks)
        rdOff[ks] = c * 128 + (((ks * 4 + g) ^ (c & 7)) * 16);

    int pWr[4];
#pragma unroll
    for (int nt = 0; nt < 4; ++nt)
        pWr[nt] = c * 128 + (((nt * 2 + (g >> 1)) ^ (c & 7)) << 4) + ((g & 1) << 3);
    int pRd[2];
#pragma unroll
    for (int ks = 0; ks < 2; ++ks)
        pRd[ks] = c * 128 + (((ks * 4 + g) ^ (c & 7)) << 4);

    const int mRowIdx = b * LQ_ + q0 + c;
    const size_t mTile0 = (size_t)(ws * 16) * 2048 + mRowIdx;

    {
#pragma unroll
        for (int j = 0; j < 2; ++j) {
            gload16_lds(kTileB + (wq * 2048 + j * 1024) + stOffBase, half + (wq * 2048 + j * 1024));
            gload16_lds(vTileB + (wq * 2048 + j * 1024) + stOffBase, half + 8192 + (wq * 2048 + j * 1024));
        }
    }
    unsigned long long mksCur = Mbt[mTile0];       // mask for tile 0 (prefetched)
    __syncthreads();

    for (int t = 0; t < 16; ++t) {
        unsigned long long mksNext = 0;
        if (t < 15) {
            const char* kt = kTileB + (size_t)(t + 1) * 8192;
            const char* vt = vTileB + (size_t)(t + 1) * 8192;
            char* dst = half + ((t + 1) & 1) * 16384;
#pragma unroll
            for (int j = 0; j < 2; ++j) {
                gload16_lds(kt + (wq * 2048 + j * 1024) + stOffBase, dst + (wq * 2048 + j * 1024));
                gload16_lds(vt + (wq * 2048 + j * 1024) + stOffBase, dst + 8192 + (wq * 2048 + j * 1024));
            }
            mksNext = Mbt[mTile0 + (size_t)(t + 1) * 2048];   // hide L2 latency under QK^T
        }

        const char* bufp = half + (t & 1) * 16384;

        f32x4 s[4];
        __builtin_amdgcn_s_setprio(1);
#pragma unroll
        for (int nt = 0; nt < 4; ++nt) {
            f32x4 accS = f32x4{0.f, 0.f, 0.f, 0.f};
#pragma unroll
            for (int ks = 0; ks < 2; ++ks) {
                f16x8 kf = *(const f16x8*)(bufp + nt * 2048 + rdOff[ks]);
                accS = __builtin_amdgcn_mfma_f32_16x16x32_f16(kf, qf[ks], accS, 0, 0, 0);
            }
            s[nt] = accS;
        }
        __builtin_amdgcn_s_setprio(0);

        unsigned long long mks = mksCur >> (g * 4);
#pragma unroll
        for (int nt = 0; nt < 4; ++nt) {
            unsigned nib = (unsigned)(mks >> (nt * 16)) & 0xFu;
            if (nib & 1u) s[nt][0] = -1e9f;
            if (nib & 2u) s[nt][1] = -1e9f;
            if (nib & 4u) s[nt][2] = -1e9f;
            if (nib & 8u) s[nt][3] = -1e9f;
        }
        // ---- lazy defer-max ----
        float t0 = fmaxf(fmaxf(s[0][0], s[0][1]), fmaxf(s[0][2], s[0][3]));
        float t1 = fmaxf(fmaxf(s[1][0], s[1][1]), fmaxf(s[1][2], s[1][3]));
        float t2 = fmaxf(fmaxf(s[2][0], s[2][1]), fmaxf(s[2][2], s[2][3]));
        float t3 = fmaxf(fmaxf(s[3][0], s[3][1]), fmaxf(s[3][2], s[3][3]));
        float tmaxl = fmaxf(fmaxf(t0, t1), fmaxf(t2, t3));
        if (!__all(tmaxl - m <= 8.0f)) {
            float tq = fmaxf(tmaxl, __shfl_xor(tmaxl, 16, 64));
            tq = fmaxf(tq, __shfl_xor(tq, 32, 64));
            float mn = fmaxf(m, tq);
            float scl = exp2f(m - mn);
            m = mn;
            lsum *= scl;
#pragma unroll
            for (int dt = 0; dt < 4; dt++)
#pragma unroll
                for (int r = 0; r < 4; r++) o[dt][r] *= scl;
        }
        // ---- exp2 + per-lane lsum; pack P and write 4 x b64 ----
        float ts = 0.f;
#pragma unroll
        for (int nt = 0; nt < 4; ++nt) {
            float p0 = exp2f(s[nt][0] - m);
            float p1 = exp2f(s[nt][1] - m);
            float p2 = exp2f(s[nt][2] - m);
            float p3 = exp2f(s[nt][3] - m);
            ts += (p0 + p1) + (p2 + p3);
            uint2v pw;
            pw.x = __builtin_bit_cast(unsigned, __builtin_amdgcn_cvt_pkrtz(p0, p1));
            pw.y = __builtin_bit_cast(unsigned, __builtin_amdgcn_cvt_pkrtz(p2, p3));
            *(uint2v*)(Pl + pWr[nt]) = pw;    // rows nt*16+4g..+3 of col c
        }
        lsum += ts;
        // ---- PV: read P B-frag (2 x b128), V from LDS ----
        __builtin_amdgcn_s_setprio(1);
#pragma unroll
        for (int ks = 0; ks < 2; ++ks) {
            f16x8 pf = *(const f16x8*)(Pl + pRd[ks]);
#pragma unroll
            for (int dt = 0; dt < 4; ++dt) {
                f16x8 vf = *(const f16x8*)(bufp + 8192 + dt * 2048 + rdOff[ks]);
                o[dt] = __builtin_amdgcn_mfma_f32_16x16x32_f16(vf, pf, o[dt], 0, 0, 0);
            }
        }
        __builtin_amdgcn_s_setprio(0);
        __syncthreads();
        mksCur = mksNext;
    }

    // ---- final per-q lsum reduce ----
    lsum += __shfl_xor(lsum, 16, 64);
    lsum += __shfl_xor(lsum, 32, 64);

    float* OfP = (float*)ldsraw;                  // [128][68]
    float* Ml  = (float*)(ldsraw + 34816);        // [128][2]
#pragma unroll
    for (int dt = 0; dt < 4; ++dt)
#pragma unroll
        for (int r = 0; r < 4; r++)
            OfP[(w * 16 + c) * 68 + dt * 16 + 4 * g + r] = o[dt][r];
    if (lane < 16) {
        Ml[(w * 16 + lane) * 2 + 0] = m;
        Ml[(w * 16 + lane) * 2 + 1] = lsum;
    }
    __syncthreads();

    const int d = tid & 63;
    const int qlBase = tid >> 6;
#pragma unroll
    for (int pass = 0; pass < 8; ++pass) {
        int ql = pass * 8 + qlBase;          // 0..63
        float m0 = Ml[ql * 2], l0 = Ml[ql * 2 + 1];
        float m1 = Ml[(64 + ql) * 2], l1 = Ml[(64 + ql) * 2 + 1];
        float M  = fmaxf(m0, m1);
        float e0 = exp2f(m0 - M), e1 = exp2f(m1 - M);
        float L  = l0 * e0 + l1 * e1;
        float acc = OfP[ql * 68 + d] * e0 + OfP[(64 + ql) * 68 + d] * e1;
        O[((size_t)b * LQ_ + qt * 64 + ql) * E_ + h * 64 + d] = (_Float16)(acc / L);
    }
}

extern "C" void kernel_launch(void* const* d_in, const int* in_sizes, int n_in,
                              void* d_out, int out_size, void* d_ws, size_t ws_size,
                              hipStream_t stream)
{
    const float* x   = (const float*)d_in[0];
    const float* ctx = (const float*)d_in[1];
    const void*  msk = d_in[2];
    const float* Wq  = (const float*)d_in[3];
    const float* Wk  = (const float*)d_in[4];
    const float* Wv  = (const float*)d_in[5];
    const float* fcw = (const float*)d_in[6];
    const float* fcb = (const float*)d_in[7];
    float* out = (float*)d_out;

    char* ws = (char*)d_ws;
    size_t off = 0;
    auto alloc = [&](size_t bytes) { char* p = ws + off; off += (bytes + 255) & ~255ull; return p; };

    int* modep = (int*)alloc(256);
    unsigned long long* Mbt = (unsigned long long*)alloc((size_t)B_ * LQ_ * (LKV_ / 64) * 8);
    _Float16* xh   = (_Float16*)alloc((size_t)B_ * LQ_ * E_ * 2);
    _Float16* ch   = (_Float16*)alloc((size_t)B_ * LKV_ * E_ * 2);
    _Float16* wqh  = (_Float16*)alloc((size_t)E_ * E_ * 2);
    _Float16* wkvh = (_Float16*)alloc((size_t)2 * E_ * E_ * 2);
    _Float16* fwh  = (_Float16*)alloc((size_t)E_ * E_ * 2);
    float*    fbf  = (float*)alloc((size_t)E_ * 4);
    _Float16* Qh   = (_Float16*)alloc((size_t)B_ * H_ * LQ_ * D_ * 2);
    _Float16* Kh   = (_Float16*)alloc((size_t)B_ * H_ * LKV_ * D_ * 2);
    _Float16* Vt   = (_Float16*)alloc((size_t)B_ * H_ * LKV_ * D_ * 2);
    _Float16* Ob   = xh;  // safe alias: gemm22_qkv (last reader of xh) finishes before attn writes Ob
    (void)ws_size; (void)in_sizes; (void)n_in; (void)out_size;

    probe22<<<1, 64, 0, stream>>>(msk, modep);

    canon22_all<<<2048, 256, 0, stream>>>(x, ctx, Wq, Wk, Wv, fcw, fcb, msk,
                                          xh, ch, wqh, wkvh, fwh, fbf, Mbt, modep);

    gemm22_qkv<<<1280, 256, 0, stream>>>(xh, ch, wqh, wkvh, Qh, Kh, Vt);

    attn22_kernel<<<512, 512, 0, stream>>>(Qh, Kh, Vt, Mbt, Ob);

    gemm22_fc<<<256, 256, 0, stream>>>(Ob, fwh, fbf, out);
}

// Round 23
// 121.135 us; speedup vs baseline: 1.2299x; 1.0299x over previous
//
#include <hip/hip_runtime.h>
#include <hip/hip_bf16.h>

#define B_   2
#define H_   16
#define LQ_  1024
#define LKV_ 2048
#define D_   64
#define E_   1024

typedef __attribute__((ext_vector_type(8))) _Float16 f16x8;
typedef __attribute__((ext_vector_type(4))) float   f32x4;
typedef __attribute__((ext_vector_type(2))) unsigned uint2v;

__device__ __forceinline__ void gload16_lds(const void* g, void* l) {
    __builtin_amdgcn_global_load_lds(
        (const __attribute__((address_space(1))) unsigned int*)g,
        (__attribute__((address_space(3))) unsigned int*)l, 16, 0, 0);
}

// ---------------- canonicalization with fused PARALLEL mask-dtype probe ----------
// (not r7's serial-probe failure: 256 threads sample 1 word each, same words
//  every block -> L2-hot; wave __any + 4 LDS atomics + 1 barrier)
__global__ void canon23_all(
    const float* __restrict__ x,  const float* __restrict__ ctx,
    const float* __restrict__ wq, const float* __restrict__ wk,
    const float* __restrict__ wv, const float* __restrict__ fw,
    const float* __restrict__ fb, const void* __restrict__ msk,
    _Float16* __restrict__ xh,  _Float16* __restrict__ ch,
    _Float16* __restrict__ wqh, _Float16* __restrict__ wkvh,
    _Float16* __restrict__ fwh, float* __restrict__ fbf,
    unsigned long long* __restrict__ Mbt)
{
    __shared__ int flags[3];
    if (threadIdx.x < 3) flags[threadIdx.x] = 0;
    __syncthreads();
    {
        unsigned v = ((const unsigned*)msk)[threadIdx.x * 997];   // max idx 255*997 < 254236 words: in-bounds all layouts
        int notInt = (v > 1u);
        int notF32 = (v != 0u && v != 0x3F800000u);
        int notBF  = (v != 0u && v != 0x3F80u && v != 0x3F800000u && v != 0x3F803F80u);
        int a0 = __any(notInt), a1 = __any(notF32), a2 = __any(notBF);
        if ((threadIdx.x & 63) == 0) {
            if (a0) atomicOr(&flags[0], 1);
            if (a1) atomicOr(&flags[1], 1);
            if (a2) atomicOr(&flags[2], 1);
        }
    }
    __syncthreads();
    const int mmode = !flags[0] ? 0 : (!flags[1] ? 1 : (!flags[2] ? 2 : 3));  // int32/f32/bf16/u8

    const int total = 1376384;
    const int stride = gridDim.x * blockDim.x;
    for (int idx = blockIdx.x * blockDim.x + threadIdx.x; idx < total; idx += stride) {
        if (idx < 1310720) {
            const float* src; _Float16* dst; int rel;
            if (idx < 262144)       { src = x;   dst = xh;   rel = idx; }
            else if (idx < 786432)  { src = ctx; dst = ch;   rel = idx - 262144; }
            else if (idx < 917504)  { src = wq;  dst = wqh;  rel = idx - 786432; }
            else if (idx < 1048576) { src = wk;  dst = wkvh; rel = idx - 917504; }
            else if (idx < 1179648) { src = wv;  dst = wkvh + (size_t)E_ * E_; rel = idx - 1048576; }
            else                    { src = fw;  dst = fwh;  rel = idx - 1179648; }
            f32x4 a = ((const f32x4*)src)[2 * rel], b = ((const f32x4*)src)[2 * rel + 1];
            f16x8 o;
            o[0] = (_Float16)a.x; o[1] = (_Float16)a.y; o[2] = (_Float16)a.z; o[3] = (_Float16)a.w;
            o[4] = (_Float16)b.x; o[5] = (_Float16)b.y; o[6] = (_Float16)b.z; o[7] = (_Float16)b.w;
            ((f16x8*)dst)[rel] = o;
        } else if (idx < 1310848) {
            int rel = idx - 1310720;
#pragma unroll
            for (int j = 0; j < 8; ++j) fbf[rel * 8 + j] = fb[rel * 8 + j];
        } else {
            int rel = idx - 1310848;           // rel = row*32 + t
            const size_t base = (size_t)rel * 64;
            unsigned long long v = 0;
            if (mmode == 0) {
                const int* p = (const int*)msk + base;
#pragma unroll
                for (int j = 0; j < 64; ++j) if (p[j] != 0) v |= 1ull << j;
            } else if (mmode == 1) {
                const float* p = (const float*)msk + base;
#pragma unroll
                for (int j = 0; j < 64; ++j) if (p[j] != 0.0f) v |= 1ull << j;
            } else if (mmode == 2) {
                const unsigned short* p = (const unsigned short*)msk + base;
#pragma unroll
                for (int j = 0; j < 64; ++j) if (p[j] != 0) v |= 1ull << j;
            } else {
                const unsigned char* p = (const unsigned char*)msk + base;
#pragma unroll
                for (int j = 0; j < 64; ++j) if (p[j] != 0) v |= 1ull << j;
            }
            Mbt[(rel & 31) * 2048 + (rel >> 5)] = v;   // transposed: [t][b*LQ+q]
        }
    }
}

// ---------------- fused Q + K|V projection GEMM: 64x128 tiles, BK=64, dbuf ----------
// XCD-aware block mapping: bid%8 is a function of tm ONLY (A-panel L2 locality).
__global__ __launch_bounds__(256) void gemm23_qkv(
    const _Float16* __restrict__ xh, const _Float16* __restrict__ ch,
    const _Float16* __restrict__ wqh, const _Float16* __restrict__ wkvh,
    _Float16* __restrict__ Qh, _Float16* __restrict__ Kh, _Float16* __restrict__ Vt)
{
    __shared__ __align__(16) _Float16 As[2][64 * 64];    // 2 x 8KB
    __shared__ __align__(16) _Float16 Bs[2][128 * 64];   // 2 x 16KB

    const int bid = blockIdx.x;
    const bool isQ = bid < 256;
    const _Float16* A; const _Float16* W; int tm, tn;
    if (isQ) { A = xh; W = wqh; tm = bid & 31; tn = bid >> 5; }
    else     { int b2 = bid - 256; A = ch; W = wkvh; tm = b2 & 63; tn = b2 >> 6; }

    const int tid = threadIdx.x;
    const int w = tid >> 6, lane = tid & 63;
    const int g = lane >> 4, c = lane & 15;
    const int wr = w >> 1, wc = w & 1;
    const int rowS = lane >> 3, slot = lane & 7;
    const int stSwz = ((slot ^ (rowS & 7)) << 4);
    const int swz0 = ((g ^ (c & 7)) << 4);
    const int swz1 = (((4 + g) ^ (c & 7)) << 4);

    f32x4 acc[2][4];
#pragma unroll
    for (int i = 0; i < 2; i++)
#pragma unroll
        for (int j = 0; j < 4; j++) acc[i][j] = f32x4{0.f, 0.f, 0.f, 0.f};

    const size_t rowB = (size_t)E_ * 2;
    const char* gAbase = (const char*)A + (size_t)(tm * 64) * rowB;
    const char* gBbase = (const char*)W + (size_t)(tn * 128) * rowB;

#pragma unroll
    for (int j = 0; j < 2; ++j) {
        int rloc = w * 16 + j * 8 + rowS;
        gload16_lds(gAbase + (size_t)rloc * rowB + stSwz,
                    (char*)As[0] + (w * 16 + j * 8) * 128 + lane * 16);
    }
#pragma unroll
    for (int j = 0; j < 4; ++j) {
        int rloc = w * 32 + j * 8 + rowS;
        gload16_lds(gBbase + (size_t)rloc * rowB + stSwz,
                    (char*)Bs[0] + (w * 32 + j * 8) * 128 + lane * 16);
    }
    __syncthreads();

    for (int kt = 0; kt < 16; ++kt) {
        if (kt < 15) {
            const int nb = (kt + 1) & 1;
#pragma unroll
            for (int j = 0; j < 2; ++j) {
                int rloc = w * 16 + j * 8 + rowS;
                gload16_lds(gAbase + (size_t)rloc * rowB + (kt + 1) * 128 + stSwz,
                            (char*)As[nb] + (w * 16 + j * 8) * 128 + lane * 16);
            }
#pragma unroll
            for (int j = 0; j < 4; ++j) {
                int rloc = w * 32 + j * 8 + rowS;
                gload16_lds(gBbase + (size_t)rloc * rowB + (kt + 1) * 128 + stSwz,
                            (char*)Bs[nb] + (w * 32 + j * 8) * 128 + lane * 16);
            }
        }
        const int cb = kt & 1;

        f16x8 bF[4][2];
#pragma unroll
        for (int ni = 0; ni < 4; ni++) {
            const char* bp = (const char*)Bs[cb] + (wc * 64 + ni * 16 + c) * 128;
            bF[ni][0] = *(const f16x8*)(bp + swz0);
            bF[ni][1] = *(const f16x8*)(bp + swz1);
        }
#pragma unroll
        for (int mi = 0; mi < 2; mi++) {
            const char* ap = (const char*)As[cb] + (wr * 32 + mi * 16 + c) * 128;
            f16x8 a0 = *(const f16x8*)(ap + swz0);
            f16x8 a1 = *(const f16x8*)(ap + swz1);
#pragma unroll
            for (int ni = 0; ni < 4; ni++) {
                acc[mi][ni] = __builtin_amdgcn_mfma_f32_16x16x32_f16(a0, bF[ni][0], acc[mi][ni], 0, 0, 0);
                acc[mi][ni] = __builtin_amdgcn_mfma_f32_16x16x32_f16(a1, bF[ni][1], acc[mi][ni], 0, 0, 0);
            }
        }
        __syncthreads();
    }

#pragma unroll
    for (int mi = 0; mi < 2; mi++) {
#pragma unroll
        for (int ni = 0; ni < 4; ni++) {
#pragma unroll
            for (int r = 0; r < 4; r++) {
                int R  = tm * 64 + wr * 32 + mi * 16 + g * 4 + r;
                int Cc = tn * 128 + wc * 64 + ni * 16 + c;
                float v = acc[mi][ni][r];
                if (isQ) {
                    int b = R >> 10, q = R & 1023;
                    int h = Cc >> 6, d = Cc & 63;
                    // 0.125 * log2(e): attention works in exp2 domain
                    Qh[((size_t)(b * H_ + h) * LQ_ + q) * D_ + d] = (_Float16)(v * 0.18033688011112042f);
                } else {
                    int b = R >> 11, k = R & 2047;
                    int isV = Cc >> 10, cc2 = Cc & 1023;
                    int h = cc2 >> 6, d = cc2 & 63;
                    if (!isV)
                        Kh[((size_t)(b * H_ + h) * LKV_ + k) * D_ + d] = (_Float16)v;
                    else {
                        size_t bh = (size_t)(b * H_ + h);
                        Vt[((bh * (LKV_ / 64) + (k >> 6)) * D_ + d) * 64 + (k & 63)] = (_Float16)v;
                    }
                }
            }
        }
    }
}

// ---------------- FC GEMM: 64x128 tiles, XCD-aware mapping, BK=64, dbuf ------------
__global__ __launch_bounds__(256) void gemm23_fc(
    const _Float16* __restrict__ A, const _Float16* __restrict__ W,
    const float* __restrict__ bias, float* __restrict__ Cout)
{
    __shared__ __align__(16) _Float16 As[2][64 * 64];
    __shared__ __align__(16) _Float16 Bs[2][128 * 64];

    const int tm = blockIdx.x & 31, tn = blockIdx.x >> 5;   // bid = tn*32 + tm
    const int tid = threadIdx.x;
    const int w = tid >> 6, lane = tid & 63;
    const int g = lane >> 4, c = lane & 15;
    const int wr = w >> 1, wc = w & 1;
    const int rowS = lane >> 3, slot = lane & 7;
    const int stSwz = ((slot ^ (rowS & 7)) << 4);
    const int swz0 = ((g ^ (c & 7)) << 4);
    const int swz1 = (((4 + g) ^ (c & 7)) << 4);

    f32x4 acc[2][4];
#pragma unroll
    for (int i = 0; i < 2; i++)
#pragma unroll
        for (int j = 0; j < 4; j++) acc[i][j] = f32x4{0.f, 0.f, 0.f, 0.f};

    const size_t rowB = (size_t)E_ * 2;
    const char* gAbase = (const char*)A + (size_t)(tm * 64) * rowB;
    const char* gBbase = (const char*)W + (size_t)(tn * 128) * rowB;

#pragma unroll
    for (int j = 0; j < 2; ++j) {
        int rloc = w * 16 + j * 8 + rowS;
        gload16_lds(gAbase + (size_t)rloc * rowB + stSwz,
                    (char*)As[0] + (w * 16 + j * 8) * 128 + lane * 16);
    }
#pragma unroll
    for (int j = 0; j < 4; ++j) {
        int rloc = w * 32 + j * 8 + rowS;
        gload16_lds(gBbase + (size_t)rloc * rowB + stSwz,
                    (char*)Bs[0] + (w * 32 + j * 8) * 128 + lane * 16);
    }
    __syncthreads();

    for (int kt = 0; kt < 16; ++kt) {
        if (kt < 15) {
            const int nb = (kt + 1) & 1;
#pragma unroll
            for (int j = 0; j < 2; ++j) {
                int rloc = w * 16 + j * 8 + rowS;
                gload16_lds(gAbase + (size_t)rloc * rowB + (kt + 1) * 128 + stSwz,
                            (char*)As[nb] + (w * 16 + j * 8) * 128 + lane * 16);
            }
#pragma unroll
            for (int j = 0; j < 4; ++j) {
                int rloc = w * 32 + j * 8 + rowS;
                gload16_lds(gBbase + (size_t)rloc * rowB + (kt + 1) * 128 + stSwz,
                            (char*)Bs[nb] + (w * 32 + j * 8) * 128 + lane * 16);
            }
        }
        const int cb = kt & 1;

        f16x8 bF[4][2];
#pragma unroll
        for (int ni = 0; ni < 4; ni++) {
            const char* bp = (const char*)Bs[cb] + (wc * 64 + ni * 16 + c) * 128;
            bF[ni][0] = *(const f16x8*)(bp + swz0);
            bF[ni][1] = *(const f16x8*)(bp + swz1);
        }
#pragma unroll
        for (int mi = 0; mi < 2; mi++) {
            const char* ap = (const char*)As[cb] + (wr * 32 + mi * 16 + c) * 128;
            f16x8 a0 = *(const f16x8*)(ap + swz0);
            f16x8 a1 = *(const f16x8*)(ap + swz1);
#pragma unroll
            for (int ni = 0; ni < 4; ni++) {
                acc[mi][ni] = __builtin_amdgcn_mfma_f32_16x16x32_f16(a0, bF[ni][0], acc[mi][ni], 0, 0, 0);
                acc[mi][ni] = __builtin_amdgcn_mfma_f32_16x16x32_f16(a1, bF[ni][1], acc[mi][ni], 0, 0, 0);
            }
        }
        __syncthreads();
    }

#pragma unroll
    for (int mi = 0; mi < 2; mi++)
#pragma unroll
        for (int ni = 0; ni < 4; ni++)
#pragma unroll
            for (int r = 0; r < 4; r++) {
                int R  = tm * 64 + wr * 32 + mi * 16 + g * 4 + r;
                int Cc = tn * 128 + wc * 64 + ni * 16 + c;
                Cout[(size_t)R * E_ + Cc] = acc[mi][ni][r] + bias[Cc];
            }
}

// ---------------- flash attention: r22 champion, verbatim ----------------
__global__ __launch_bounds__(512) void attn23_kernel(
    const _Float16* __restrict__ Qh,   // [B,H,LQ,D] pre-scaled by 0.125*log2e
    const _Float16* __restrict__ Kh,   // [B,H,LKV,D]
    const _Float16* __restrict__ Vt,   // [B*H][LKV/64][D][64] tiled
    const unsigned long long* __restrict__ Mbt,  // [32][B*LQ] transposed bitmask
    _Float16* __restrict__ O)          // [B,LQ,E] f16
{
    __shared__ __align__(16) char ldsraw[81920];  // [0,64K) K/V dbuf halves; [64K,80K) P per-wave

    const int bid0 = blockIdx.x;
    const int xcd = bid0 & 7, jj = bid0 >> 3;
    const int bh = xcd * 4 + (jj >> 4);
    const int qt = jj & 15;
    const int b = bh >> 4, h = bh & 15;
    const int tid = threadIdx.x;
    const int w = tid >> 6, lane = tid & 63;
    const int g = lane >> 4, c = lane & 15;
    const int ws = w >> 2, wq = w & 3;
    const int q0 = qt * 64 + wq * 16;

    char* half = ldsraw + ws * 32768;
    char* Pl   = ldsraw + 65536 + w * 2048;   // per-wave [q=c][kv 64] f16, slot-swizzled

    f16x8 qf[2];
#pragma unroll
    for (int ks = 0; ks < 2; ++ks)
        qf[ks] = *(const f16x8*)&Qh[((size_t)bh * LQ_ + q0 + c) * D_ + ks * 32 + g * 8];

    f32x4 o[4];
#pragma unroll
    for (int dt = 0; dt < 4; dt++) o[dt] = f32x4{0.f, 0.f, 0.f, 0.f};
    float m = -1e30f, lsum = 0.f;   // lsum = per-lane partial

    const int rowS = (lane >> 3);
    const int stOffBase = (rowS * 128) + (((lane & 7) ^ (rowS & 7)) * 16);
    const char* kTileB = (const char*)Kh + (size_t)bh * (LKV_ * D_ * 2) + (size_t)ws * 16 * 8192;
    const char* vTileB = (const char*)Vt + (size_t)bh * (LKV_ * D_ * 2) + (size_t)ws * 16 * 8192;

    int rdOff[2];
#pragma unroll
    for (int ks = 0; ks < 2; ++ks)
        rdOff[ks] = c * 128 + (((ks * 4 + g) ^ (c & 7)) * 16);

    int pWr[4];
#pragma unroll
    for (int nt = 0; nt < 4; ++nt)
        pWr[nt] = c * 128 + (((nt * 2 + (g >> 1)) ^ (c & 7)) << 4) + ((g & 1) << 3);
    int pRd[2];
#pragma unroll
    for (int ks = 0; ks < 2; ++ks)
        pRd[ks] = c * 128 + (((ks * 4 + g) ^ (c & 7)) << 4);

    const int mRowIdx = b * LQ_ + q0 + c;
    const size_t mTile0 = (size_t)(ws * 16) * 2048 + mRowIdx;

    {
#pragma unroll
        for (int j = 0; j < 2; ++j) {
            gload16_lds(kTileB + (wq * 2048 + j * 1024) + stOffBase, half + (wq * 2048 + j * 1024));
            gload16_lds(vTileB + (wq * 2048 + j * 1024) + stOffBase, half + 8192 + (wq * 2048 + j * 1024));
        }
    }
    unsigned long long mksCur = Mbt[mTile0];       // mask for tile 0 (prefetched)
    __syncthreads();

    for (int t = 0; t < 16; ++t) {
        unsigned long long mksNext = 0;
        if (t < 15) {
            const char* kt = kTileB + (size_t)(t + 1) * 8192;
            const char* vt = vTileB + (size_t)(t + 1) * 8192;
            char* dst = half + ((t + 1) & 1) * 16384;
#pragma unroll
            for (int j = 0; j < 2; ++j) {
                gload16_lds(kt + (wq * 2048 + j * 1024) + stOffBase, dst + (wq * 2048 + j * 1024));
                gload16_lds(vt + (wq * 2048 + j * 1024) + stOffBase, dst + 8192 + (wq * 2048 + j * 1024));
            }
            mksNext = Mbt[mTile0 + (size_t)(t + 1) * 2048];   // hide L2 latency under QK^T
        }

        const char* bufp = half + (t & 1) * 16384;

        f32x4 s[4];
        __builtin_amdgcn_s_setprio(1);
#pragma unroll
        for (int nt = 0; nt < 4; ++nt) {
            f32x4 accS = f32x4{0.f, 0.f, 0.f, 0.f};
#pragma unroll
            for (int ks = 0; ks < 2; ++ks) {
                f16x8 kf = *(const f16x8*)(bufp + nt * 2048 + rdOff[ks]);
                accS = __builtin_amdgcn_mfma_f32_16x16x32_f16(kf, qf[ks], accS, 0, 0, 0);
            }
            s[nt] = accS;
        }
        __builtin_amdgcn_s_setprio(0);

        unsigned long long mks = mksCur >> (g * 4);
#pragma unroll
        for (int nt = 0; nt < 4; ++nt) {
            unsigned nib = (unsigned)(mks >> (nt * 16)) & 0xFu;
            if (nib & 1u) s[nt][0] = -1e9f;
            if (nib & 2u) s[nt][1] = -1e9f;
            if (nib & 4u) s[nt][2] = -1e9f;
            if (nib & 8u) s[nt][3] = -1e9f;
        }
        // ---- lazy defer-max ----
        float t0 = fmaxf(fmaxf(s[0][0], s[0][1]), fmaxf(s[0][2], s[0][3]));
        float t1 = fmaxf(fmaxf(s[1][0], s[1][1]), fmaxf(s[1][2], s[1][3]));
        float t2 = fmaxf(fmaxf(s[2][0], s[2][1]), fmaxf(s[2][2], s[2][3]));
        float t3 = fmaxf(fmaxf(s[3][0], s[3][1]), fmaxf(s[3][2], s[3][3]));
        float tmaxl = fmaxf(fmaxf(t0, t1), fmaxf(t2, t3));
        if (!__all(tmaxl - m <= 8.0f)) {
            float tq = fmaxf(tmaxl, __shfl_xor(tmaxl, 16, 64));
            tq = fmaxf(tq, __shfl_xor(tq, 32, 64));
            float mn = fmaxf(m, tq);
            float scl = exp2f(m - mn);
            m = mn;
            lsum *= scl;
#pragma unroll
            for (int dt = 0; dt < 4; dt++)
#pragma unroll
                for (int r = 0; r < 4; r++) o[dt][r] *= scl;
        }
        // ---- exp2 + per-lane lsum; pack P and write 4 x b64 ----
        float ts = 0.f;
#pragma unroll
        for (int nt = 0; nt < 4; ++nt) {
            float p0 = exp2f(s[nt][0] - m);
            float p1 = exp2f(s[nt][1] - m);
            float p2 = exp2f(s[nt][2] - m);
            float p3 = exp2f(s[nt][3] - m);
            ts += (p0 + p1) + (p2 + p3);
            uint2v pw;
            pw.x = __builtin_bit_cast(unsigned, __builtin_amdgcn_cvt_pkrtz(p0, p1));
            pw.y = __builtin_bit_cast(unsigned, __builtin_amdgcn_cvt_pkrtz(p2, p3));
            *(uint2v*)(Pl + pWr[nt]) = pw;    // rows nt*16+4g..+3 of col c
        }
        lsum += ts;
        // ---- PV: read P B-frag (2 x b128), V from LDS ----
        __builtin_amdgcn_s_setprio(1);
#pragma unroll
        for (int ks = 0; ks < 2; ++ks) {
            f16x8 pf = *(const f16x8*)(Pl + pRd[ks]);
#pragma unroll
            for (int dt = 0; dt < 4; ++dt) {
                f16x8 vf = *(const f16x8*)(bufp + 8192 + dt * 2048 + rdOff[ks]);
                o[dt] = __builtin_amdgcn_mfma_f32_16x16x32_f16(vf, pf, o[dt], 0, 0, 0);
            }
        }
        __builtin_amdgcn_s_setprio(0);
        __syncthreads();
        mksCur = mksNext;
    }

    // ---- final per-q lsum reduce ----
    lsum += __shfl_xor(lsum, 16, 64);
    lsum += __shfl_xor(lsum, 32, 64);

    float* OfP = (float*)ldsraw;                  // [128][68]
    float* Ml  = (float*)(ldsraw + 34816);        // [128][2]
#pragma unroll
    for (int dt = 0; dt < 4; ++dt)
#pragma unroll
        for (int r = 0; r < 4; r++)
            OfP[(w * 16 + c) * 68 + dt * 16 + 4 * g + r] = o[dt][r];
    if (lane < 16) {
        Ml[(w * 16 + lane) * 2 + 0] = m;
        Ml[(w * 16 + lane) * 2 + 1] = lsum;
    }
    __syncthreads();

    const int d = tid & 63;
    const int qlBase = tid >> 6;
#pragma unroll
    for (int pass = 0; pass < 8; ++pass) {
        int ql = pass * 8 + qlBase;          // 0..63
        float m0 = Ml[ql * 2], l0 = Ml[ql * 2 + 1];
        float m1 = Ml[(64 + ql) * 2], l1 = Ml[(64 + ql) * 2 + 1];
        float M  = fmaxf(m0, m1);
        float e0 = exp2f(m0 - M), e1 = exp2f(m1 - M);
        float L  = l0 * e0 + l1 * e1;
        float acc = OfP[ql * 68 + d] * e0 + OfP[(64 + ql) * 68 + d] * e1;
        O[((size_t)b * LQ_ + qt * 64 + ql) * E_ + h * 64 + d] = (_Float16)(acc / L);
    }
}

extern "C" void kernel_launch(void* const* d_in, const int* in_sizes, int n_in,
                              void* d_out, int out_size, void* d_ws, size_t ws_size,
                              hipStream_t stream)
{
    const float* x   = (const float*)d_in[0];
    const float* ctx = (const float*)d_in[1];
    const void*  msk = d_in[2];
    const float* Wq  = (const float*)d_in[3];
    const float* Wk  = (const float*)d_in[4];
    const float* Wv  = (const float*)d_in[5];
    const float* fcw = (const float*)d_in[6];
    const float* fcb = (const float*)d_in[7];
    float* out = (float*)d_out;

    char* ws = (char*)d_ws;
    size_t off = 0;
    auto alloc = [&](size_t bytes) { char* p = ws + off; off += (bytes + 255) & ~255ull; return p; };

    unsigned long long* Mbt = (unsigned long long*)alloc((size_t)B_ * LQ_ * (LKV_ / 64) * 8);
    _Float16* xh   = (_Float16*)alloc((size_t)B_ * LQ_ * E_ * 2);
    _Float16* ch   = (_Float16*)alloc((size_t)B_ * LKV_ * E_ * 2);
    _Float16* wqh  = (_Float16*)alloc((size_t)E_ * E_ * 2);
    _Float16* wkvh = (_Float16*)alloc((size_t)2 * E_ * E_ * 2);
    _Float16* fwh  = (_Float16*)alloc((size_t)E_ * E_ * 2);
    float*    fbf  = (float*)alloc((size_t)E_ * 4);
    _Float16* Qh   = (_Float16*)alloc((size_t)B_ * H_ * LQ_ * D_ * 2);
    _Float16* Kh   = (_Float16*)alloc((size_t)B_ * H_ * LKV_ * D_ * 2);
    _Float16* Vt   = (_Float16*)alloc((size_t)B_ * H_ * LKV_ * D_ * 2);
    _Float16* Ob   = xh;  // safe alias: gemm23_qkv (last reader of xh) finishes before attn writes Ob
    (void)ws_size; (void)in_sizes; (void)n_in; (void)out_size;

    canon23_all<<<2048, 256, 0, stream>>>(x, ctx, Wq, Wk, Wv, fcw, fcb, msk,
                                          xh, ch, wqh, wkvh, fwh, fbf, Mbt);

    gemm23_qkv<<<1280, 256, 0, stream>>>(xh, ch, wqh, wkvh, Qh, Kh, Vt);

    attn23_kernel<<<512, 512, 0, stream>>>(Qh, Kh, Vt, Mbt, Ob);

    gemm23_fc<<<256, 256, 0, stream>>>(Ob, fwh, fbf, out);
}